// Round 7
// baseline (748.568 us; speedup 1.0000x reference)
//
#include <hip/hip_runtime.h>
#include <hip/hip_bf16.h>
#include <math.h>

#define N_NODES 50000
#define N_EDGES 1600000
#define IN_DIM 16
#define HID 64
#define NBLK 6250          // N_EDGES / 256

typedef __attribute__((ext_vector_type(8))) short short8v;
typedef __attribute__((ext_vector_type(16))) float f32x16;

union U32x4S8 { unsigned u[4]; short8v s; };

__device__ __forceinline__ float lrelu(float v) { return v > 0.f ? v : 0.2f * v; }

__device__ __forceinline__ float wave_reduce_sum(float v) {
    #pragma unroll
    for (int off = 32; off > 0; off >>= 1) v += __shfl_down(v, off, 64);
    return v;
}
__device__ __forceinline__ int wave_red_sum_i(int v) {
    #pragma unroll
    for (int off = 32; off > 0; off >>= 1) v += __shfl_down(v, off, 64);
    return v;
}

// online-softmax state update / merge
__device__ __forceinline__ void sm_upd(float& m, float& den, float& acc, float e, float v) {
    float n = fmaxf(m, e);
    float f = __expf(m - n), w = __expf(e - n);
    den = den * f + w;
    acc = acc * f + w * v;
    m = n;
}
__device__ __forceinline__ void sm_merge(float& m, float& den, float& acc,
                                         float m2, float den2, float acc2) {
    float mm = fmaxf(m, m2);
    float f1 = __expf(m - mm), f2 = __expf(m2 - mm);
    den = den * f1 + den2 * f2;
    acc = acc * f1 + acc2 * f2;
    m = mm;
}

__device__ __forceinline__ unsigned pk_bf16(float a, float b) {
    unsigned ua = (unsigned)__bfloat16_as_ushort(__float2bfloat16(a));
    unsigned ub = (unsigned)__bfloat16_as_ushort(__float2bfloat16(b));
    return ua | (ub << 16);
}
__device__ __forceinline__ void hilo2(float f0, float f1, unsigned& hw, unsigned& lw) {
    __hip_bfloat16 h0 = __float2bfloat16(f0), h1 = __float2bfloat16(f1);
    float r0 = __bfloat162float(h0), r1 = __bfloat162float(h1);
    hw = (unsigned)__bfloat16_as_ushort(h0) | ((unsigned)__bfloat16_as_ushort(h1) << 16);
    lw = pk_bf16(f0 - r0, f1 - r1);
}

// qs[i][h] = sum_c W1[i, h*64+c] * as1[h,c]  (and qd with ad1)
__global__ void k_qprep(const float* __restrict__ W1, const float* __restrict__ as1,
                        const float* __restrict__ ad1, float* __restrict__ qs, float* __restrict__ qd) {
    int t = threadIdx.x;
    if (t < 32) {
        int i = t >> 1, h = t & 1;
        float s = 0.f, d = 0.f;
        for (int c = 0; c < 64; c++) {
            float w = W1[i * 128 + h * 64 + c];
            s = fmaf(w, as1[h * 64 + c], s);
            d = fmaf(w, ad1[h * 64 + c], d);
        }
        qs[i * 2 + h] = s; qd[i * 2 + h] = d;
    }
}

__global__ void k1n(const float* __restrict__ x, const float* __restrict__ qs,
                    const float* __restrict__ qd, float* __restrict__ al_s, float* __restrict__ al_d) {
    int n = blockIdx.x * 256 + threadIdx.x;
    if (n >= N_NODES) return;
    float s0 = 0.f, s1 = 0.f, d0 = 0.f, d1 = 0.f;
    #pragma unroll
    for (int i = 0; i < IN_DIM; i++) {
        float xv = x[n * IN_DIM + i];
        s0 = fmaf(xv, qs[i * 2 + 0], s0);
        s1 = fmaf(xv, qs[i * 2 + 1], s1);
        d0 = fmaf(xv, qd[i * 2 + 0], d0);
        d1 = fmaf(xv, qd[i * 2 + 1], d1);
    }
    al_s[n * 2 + 0] = s0; al_s[n * 2 + 1] = s1;
    al_d[n * 2 + 0] = d0; al_d[n * 2 + 1] = d1;
}

// CSR build
__global__ void k_hist(const int* __restrict__ dst, int* __restrict__ deg) {
    int e = blockIdx.x * blockDim.x + threadIdx.x;
    if (e < N_EDGES) atomicAdd(&deg[dst[e]], 1);
}

#define SCAN_B 256
__global__ void k_scan1(const int* __restrict__ deg, int* __restrict__ off, int* __restrict__ bsum) {
    __shared__ int sh[SCAN_B];
    int gid = blockIdx.x * SCAN_B + threadIdx.x;
    int v = (gid < N_NODES) ? deg[gid] : 0;
    sh[threadIdx.x] = v;
    __syncthreads();
    for (int o = 1; o < SCAN_B; o <<= 1) {
        int t = (threadIdx.x >= o) ? sh[threadIdx.x - o] : 0;
        __syncthreads();
        sh[threadIdx.x] += t;
        __syncthreads();
    }
    int incl = sh[threadIdx.x];
    if (gid < N_NODES) off[gid] = incl - v;
    if (threadIdx.x == SCAN_B - 1) bsum[blockIdx.x] = incl;
}
__global__ void k_scan2(int* __restrict__ bsum, int nblocks) {
    __shared__ int sh[SCAN_B];
    int v = (threadIdx.x < nblocks) ? bsum[threadIdx.x] : 0;
    sh[threadIdx.x] = v;
    __syncthreads();
    for (int o = 1; o < SCAN_B; o <<= 1) {
        int t = (threadIdx.x >= o) ? sh[threadIdx.x - o] : 0;
        __syncthreads();
        sh[threadIdx.x] += t;
        __syncthreads();
    }
    if (threadIdx.x < nblocks) bsum[threadIdx.x] = sh[threadIdx.x] - v;
}
__global__ void k_scan3(int* __restrict__ off, const int* __restrict__ bsum, int* __restrict__ cursor) {
    int gid = blockIdx.x * SCAN_B + threadIdx.x;
    if (gid < N_NODES) {
        int o = off[gid] + bsum[blockIdx.x];
        off[gid] = o;
        cursor[gid] = o;
    }
    if (gid == 0) off[N_NODES] = N_EDGES;
}
__global__ void k_scatter3(const int* __restrict__ src, const int* __restrict__ dst,
                           int* __restrict__ cursor, int* __restrict__ ssrc,
                           int* __restrict__ sdst, int* __restrict__ eid) {
    int e = blockIdx.x * blockDim.x + threadIdx.x;
    if (e < N_EDGES) {
        int d = dst[e];
        int pos = atomicAdd(&cursor[d], 1);
        ssrc[pos] = src[e];
        sdst[pos] = d;
        eid[pos] = e;
    }
}

// ---- stable 7-bucket partition by src>>13 (keeps dst order within bucket) ----
__global__ __launch_bounds__(256) void p_hist(const int* __restrict__ ssrc, int* __restrict__ cnt) {
    __shared__ int c[7];
    if (threadIdx.x < 7) c[threadIdx.x] = 0;
    __syncthreads();
    int i = blockIdx.x * 256 + threadIdx.x;
    atomicAdd(&c[ssrc[i] >> 13], 1);
    __syncthreads();
    if (threadIdx.x < 7) cnt[threadIdx.x * NBLK + blockIdx.x] = c[threadIdx.x];
}

// one block, 8 waves; wave k (<7) owns bucket k
__global__ __launch_bounds__(512) void p_scan(const int* __restrict__ cnt, int* __restrict__ basep) {
    __shared__ int tot[8];
    int wid = threadIdx.x >> 6, lane = threadIdx.x & 63;
    if (wid < 7) {
        int sum = 0;
        for (int c = 0; c < NBLK; c += 64) {
            int idx = c + lane;
            if (idx < NBLK) sum += cnt[wid * NBLK + idx];
        }
        sum = wave_red_sum_i(sum);
        if (lane == 0) tot[wid] = sum;
    }
    __syncthreads();
    if (threadIdx.x == 0) {
        int run = 0;
        for (int k = 0; k < 7; k++) { int t = tot[k]; tot[k] = run; run += t; }
    }
    __syncthreads();
    if (wid < 7) {
        int carry = tot[wid];
        for (int c = 0; c < NBLK; c += 64) {
            int idx = c + lane;
            int v = (idx < NBLK) ? cnt[wid * NBLK + idx] : 0;
            int iv = v;
            #pragma unroll
            for (int o = 1; o < 64; o <<= 1) { int t = __shfl_up(iv, o, 64); if (lane >= o) iv += t; }
            if (idx < NBLK) basep[wid * NBLK + idx] = carry + (iv - v);
            carry += __shfl(iv, 63, 64);
        }
    }
}

__global__ __launch_bounds__(256) void p_scatter(
    const int* __restrict__ ssrc, const int* __restrict__ sdst, const int* __restrict__ eid,
    const int* __restrict__ basep, int* __restrict__ s2s, int* __restrict__ s2d, int* __restrict__ e2) {
    __shared__ int wcnt[4][7];
    int wid = threadIdx.x >> 6, lane = threadIdx.x & 63;
    int i = blockIdx.x * 256 + threadIdx.x;
    int s = ssrc[i], d = sdst[i], e = eid[i];
    int k = s >> 13;
    int rank = 0;
    #pragma unroll
    for (int kk = 0; kk < 7; kk++) {
        unsigned long long m = __ballot(k == kk);
        if (k == kk) rank = __popcll(m & ((1ull << lane) - 1ull));
        if (lane == kk) wcnt[wid][kk] = __popcll(m);
    }
    __syncthreads();
    int prev = 0;
    #pragma unroll
    for (int w = 0; w < 4; w++) if (w < wid) prev += wcnt[w][k];
    int pos = basep[k * NBLK + blockIdx.x] + prev + rank;
    s2s[pos] = s; s2d[pos] = d; e2[pos] = e;
}

// K3n: layer-1 aggregation in x-space, 8 independent online-softmax chains.
__global__ void k3n(const float* __restrict__ x, const float* __restrict__ als,
                    const float* __restrict__ ald, const int* __restrict__ off,
                    const int* __restrict__ ssrc, float* __restrict__ accx,
                    float* __restrict__ denb) {
    int wid = threadIdx.x >> 6, lane = threadIdx.x & 63;
    int half = lane >> 5, sub = lane & 31, head = sub >> 4, ch = sub & 15;
    int d = blockIdx.x * 8 + wid * 2 + half;
    if (d >= N_NODES) return;
    int beg = off[d], end = off[d + 1];
    float adv = ald[d * 2 + head];
    float m[8], den[8], acc[8];
    m[0] = lrelu(als[d * 2 + head] + adv); den[0] = 1.f; acc[0] = x[d * IN_DIM + ch];
    #pragma unroll
    for (int t = 1; t < 8; t++) { m[t] = -1e30f; den[t] = 0.f; acc[t] = 0.f; }
    int i = beg;
    for (; i + 7 < end; i += 8) {
        int sv[8]; float ev[8], xv[8];
        #pragma unroll
        for (int t = 0; t < 8; t++) sv[t] = ssrc[i + t];
        #pragma unroll
        for (int t = 0; t < 8; t++) ev[t] = lrelu(als[sv[t] * 2 + head] + adv);
        #pragma unroll
        for (int t = 0; t < 8; t++) xv[t] = x[sv[t] * IN_DIM + ch];
        #pragma unroll
        for (int t = 0; t < 8; t++) sm_upd(m[t], den[t], acc[t], ev[t], xv[t]);
    }
    for (; i < end; i++) {
        int s = ssrc[i];
        sm_upd(m[0], den[0], acc[0], lrelu(als[s * 2 + head] + adv), x[s * IN_DIM + ch]);
    }
    #pragma unroll
    for (int t = 4; t < 8; t++) sm_merge(m[t - 4], den[t - 4], acc[t - 4], m[t], den[t], acc[t]);
    sm_merge(m[0], den[0], acc[0], m[1], den[1], acc[1]);
    sm_merge(m[2], den[2], acc[2], m[3], den[3], acc[3]);
    sm_merge(m[0], den[0], acc[0], m[2], den[2], acc[2]);
    accx[d * 32 + sub] = acc[0];
    if ((sub & 15) == 0) denb[d * 2 + head] = den[0];
}

// K4n: fused out1-expand then @ W2 -> h2, al_s2/al_d2.
__global__ __launch_bounds__(256) void k4n(
    const float* __restrict__ accx, const float* __restrict__ denb,
    const float* __restrict__ W1, const float* __restrict__ b1,
    const float* __restrict__ W2, const float* __restrict__ as2, const float* __restrict__ ad2,
    float* __restrict__ h2, float* __restrict__ al_s, float* __restrict__ al_d) {
    __shared__ float W1s[16 * 128];
    __shared__ float W2s[128 * 64];
    __shared__ float st[4][160];
    for (int t = threadIdx.x; t < 16 * 128; t += 256) W1s[t] = W1[t];
    for (int t = threadIdx.x; t < 128 * 64; t += 256) W2s[t] = W2[t];
    __syncthreads();
    int wid = threadIdx.x >> 6, lane = threadIdx.x & 63;
    int n = blockIdx.x * 4 + wid;
    if (n >= N_NODES) return;
    if (lane < 32) st[wid][lane] = accx[n * 32 + lane];
    float den0 = denb[n * 2], den1 = denb[n * 2 + 1];
    float ta = 0.f, tb = 0.f;
    #pragma unroll
    for (int i = 0; i < 16; i++) {
        ta = fmaf(st[wid][i],      W1s[i * 128 + lane],      ta);
        tb = fmaf(st[wid][16 + i], W1s[i * 128 + 64 + lane], tb);
    }
    ta = fmaxf(ta / den0 + b1[lane], 0.f);
    tb = fmaxf(tb / den1 + b1[64 + lane], 0.f);
    st[wid][32 + lane] = ta;
    st[wid][96 + lane] = tb;
    float acc = 0.f;
    #pragma unroll 8
    for (int k = 0; k < 128; k++) acc = fmaf(st[wid][32 + k], W2s[k * 64 + lane], acc);
    h2[n * 64 + lane] = acc;
    float ps = wave_reduce_sum(acc * as2[lane]);
    float pd = wave_reduce_sum(acc * ad2[lane]);
    if (lane == 0) { al_s[n] = ps; al_d[n] = pd; }
}

// K5a: layer-2 aggregation, one dst per 64-thread block, 8 chains, no LDS.
__global__ __launch_bounds__(64) void k5a(
    const float* __restrict__ h2, const float* __restrict__ als, const float* __restrict__ ald,
    const float* __restrict__ b2, const int* __restrict__ off, const int* __restrict__ ssrc,
    float* __restrict__ out2) {
    int d = blockIdx.x;
    int lane = threadIdx.x;
    int beg = off[d], end = off[d + 1];
    float adv = ald[d];
    float m[8], den[8], acc[8];
    m[0] = lrelu(als[d] + adv); den[0] = 1.f; acc[0] = h2[d * 64 + lane];
    #pragma unroll
    for (int t = 1; t < 8; t++) { m[t] = -1e30f; den[t] = 0.f; acc[t] = 0.f; }
    int i = beg;
    for (; i + 7 < end; i += 8) {
        int sv[8]; float ev[8], vv[8];
        #pragma unroll
        for (int t = 0; t < 8; t++) sv[t] = ssrc[i + t];
        #pragma unroll
        for (int t = 0; t < 8; t++) ev[t] = lrelu(als[sv[t]] + adv);
        #pragma unroll
        for (int t = 0; t < 8; t++) vv[t] = h2[sv[t] * 64 + lane];
        #pragma unroll
        for (int t = 0; t < 8; t++) sm_upd(m[t], den[t], acc[t], ev[t], vv[t]);
    }
    for (; i < end; i++) {
        int s = ssrc[i];
        sm_upd(m[0], den[0], acc[0], lrelu(als[s] + adv), h2[s * 64 + lane]);
    }
    #pragma unroll
    for (int t = 4; t < 8; t++) sm_merge(m[t - 4], den[t - 4], acc[t - 4], m[t], den[t], acc[t]);
    sm_merge(m[0], den[0], acc[0], m[1], den[1], acc[1]);
    sm_merge(m[2], den[2], acc[2], m[3], den[3], acc[3]);
    sm_merge(m[0], den[0], acc[0], m[2], den[2], acc[2]);
    out2[d * 64 + lane] = fmaxf(acc[0] / den[0] + b2[lane], 0.f);
}

// K5b: U = out2 @ mW1[0:64,:] + mb1, V = out2 @ mW1[64:128,:].
__global__ __launch_bounds__(256) void k5b(const float* out2, const float* __restrict__ mW1,
                                           const float* __restrict__ mb1,
                                           float* U, float* __restrict__ V) {
    __shared__ float Ws[128 * 64];
    __shared__ float o2s[4][64];
    for (int t = threadIdx.x; t < 128 * 64; t += 256) Ws[t] = mW1[t];
    __syncthreads();
    int wid = threadIdx.x >> 6, lane = threadIdx.x & 63;
    int n = blockIdx.x * 4 + wid;
    if (n >= N_NODES) return;
    o2s[wid][lane] = out2[n * 64 + lane];
    float au = mb1[lane], av = 0.f;
    #pragma unroll 8
    for (int k = 0; k < 64; k++) {
        float ov = o2s[wid][k];
        au = fmaf(ov, Ws[k * 64 + lane], au);
        av = fmaf(ov, Ws[(64 + k) * 64 + lane], av);
    }
    U[n * 64 + lane] = au;
    V[n * 64 + lane] = av;
}

// weight prep: bf16 hi/lo split of mW2^T, mW3^T
__global__ void k_wprep(const float* __restrict__ mW2, const float* __restrict__ mW3,
                        unsigned short* __restrict__ W2th, unsigned short* __restrict__ W2tl,
                        unsigned short* __restrict__ W3th, unsigned short* __restrict__ W3tl) {
    int b = blockIdx.x, t = threadIdx.x;
    float w2 = mW2[t * 64 + b];
    __hip_bfloat16 h2 = __float2bfloat16(w2);
    W2th[b * 64 + t] = __bfloat16_as_ushort(h2);
    W2tl[b * 64 + t] = __bfloat16_as_ushort(__float2bfloat16(w2 - __bfloat162float(h2)));
    float w3 = mW3[t * 64 + b];
    __hip_bfloat16 h3 = __float2bfloat16(w3);
    W3th[b * 64 + t] = __bfloat16_as_ushort(h3);
    W3tl[b * 64 + t] = __bfloat16_as_ushort(__float2bfloat16(w3 - __bfloat162float(h3)));
}

// K7d: edge MLP via MFMA, edges in (src-block, dst) 2D-local order; out via eid.
__global__ __launch_bounds__(256) void k7d(
    const int* __restrict__ ssrc, const int* __restrict__ sdst, const int* __restrict__ eid,
    const float* __restrict__ Ub, const float* __restrict__ Vb,
    const unsigned short* __restrict__ W2th, const unsigned short* __restrict__ W2tl,
    const unsigned short* __restrict__ W3th, const unsigned short* __restrict__ W3tl,
    const float* __restrict__ mb2, const float* __restrict__ mb3,
    const float* __restrict__ mW4, const float* __restrict__ mb4,
    float* __restrict__ out)
{
    const int wid = threadIdx.x >> 6, lane = threadIdx.x & 63;
    const int ebase = blockIdx.x * 256 + wid * 64;
    const int l31 = lane & 31;
    const int h = lane >> 5;
    const int ksub = h * 8;

    int rfull = ssrc[ebase + lane];
    int cfull = sdst[ebase + lane];
    int efull = eid[ebase + lane];
    float b4v = mb4[0];

    #pragma unroll 1
    for (int nB = 0; nB < 2; nB++) {
        int rA = __shfl(rfull, nB * 32 + l31, 64);
        int cA = __shfl(cfull, nB * 32 + l31, 64);
        const float* urow = Ub + rA * 64 + ksub;
        const float* vrow = Vb + cA * 64 + ksub;

        f32x16 c2[2];
        #pragma unroll
        for (int mA = 0; mA < 2; mA++)
            #pragma unroll
            for (int r = 0; r < 16; r++)
                c2[mA][r] = mb2[mA * 32 + (r & 3) + 8 * (r >> 2) + 4 * h];

        #pragma unroll
        for (int kb = 0; kb < 4; kb++) {
            float4 u0 = *(const float4*)(urow + kb * 16);
            float4 u1 = *(const float4*)(urow + kb * 16 + 4);
            float4 v0 = *(const float4*)(vrow + kb * 16);
            float4 v1 = *(const float4*)(vrow + kb * 16 + 4);
            float z[8];
            z[0] = fmaxf(u0.x + v0.x, 0.f); z[1] = fmaxf(u0.y + v0.y, 0.f);
            z[2] = fmaxf(u0.z + v0.z, 0.f); z[3] = fmaxf(u0.w + v0.w, 0.f);
            z[4] = fmaxf(u1.x + v1.x, 0.f); z[5] = fmaxf(u1.y + v1.y, 0.f);
            z[6] = fmaxf(u1.z + v1.z, 0.f); z[7] = fmaxf(u1.w + v1.w, 0.f);
            U32x4S8 bh, bl;
            #pragma unroll
            for (int q = 0; q < 4; q++) hilo2(z[2 * q], z[2 * q + 1], bh.u[q], bl.u[q]);
            #pragma unroll
            for (int mA = 0; mA < 2; mA++) {
                const int wrow = (mA * 32 + l31) * 64 + kb * 16 + ksub;
                short8v ah = *(const short8v*)(W2th + wrow);
                short8v al = *(const short8v*)(W2tl + wrow);
                c2[mA] = __builtin_amdgcn_mfma_f32_32x32x16_bf16(ah, bh.s, c2[mA], 0, 0, 0);
                c2[mA] = __builtin_amdgcn_mfma_f32_32x32x16_bf16(al, bh.s, c2[mA], 0, 0, 0);
                c2[mA] = __builtin_amdgcn_mfma_f32_32x32x16_bf16(ah, bl.s, c2[mA], 0, 0, 0);
                c2[mA] = __builtin_amdgcn_mfma_f32_32x32x16_bf16(al, bl.s, c2[mA], 0, 0, 0);
            }
        }

        f32x16 c3[2];
        #pragma unroll
        for (int mA = 0; mA < 2; mA++)
            #pragma unroll
            for (int r = 0; r < 16; r++)
                c3[mA][r] = mb3[mA * 32 + (r & 3) + 8 * (r >> 2) + 4 * h];

        #pragma unroll
        for (int kbp = 0; kbp < 4; kbp++) {
            const int mAs = kbp >> 1, kbl = kbp & 1;
            float e[8];
            #pragma unroll
            for (int b = 0; b < 4; b++) {
                float u = fmaxf(c2[mAs][8 * kbl + b], 0.f);
                float v = fmaxf(c2[mAs][8 * kbl + 4 + b], 0.f);
                float su = __shfl_xor(u, 32, 64);
                float sv = __shfl_xor(v, 32, 64);
                e[b]     = h ? sv : u;
                e[4 + b] = h ? v : su;
            }
            U32x4S8 bh, bl;
            #pragma unroll
            for (int q = 0; q < 4; q++) hilo2(e[2 * q], e[2 * q + 1], bh.u[q], bl.u[q]);
            #pragma unroll
            for (int mA = 0; mA < 2; mA++) {
                const int wrow = (mA * 32 + l31) * 64 + kbp * 16 + ksub;
                short8v ah = *(const short8v*)(W3th + wrow);
                short8v al = *(const short8v*)(W3tl + wrow);
                c3[mA] = __builtin_amdgcn_mfma_f32_32x32x16_bf16(ah, bh.s, c3[mA], 0, 0, 0);
                c3[mA] = __builtin_amdgcn_mfma_f32_32x32x16_bf16(al, bh.s, c3[mA], 0, 0, 0);
                c3[mA] = __builtin_amdgcn_mfma_f32_32x32x16_bf16(ah, bl.s, c3[mA], 0, 0, 0);
                c3[mA] = __builtin_amdgcn_mfma_f32_32x32x16_bf16(al, bl.s, c3[mA], 0, 0, 0);
            }
        }

        float p = 0.f;
        #pragma unroll
        for (int mA = 0; mA < 2; mA++)
            #pragma unroll
            for (int r = 0; r < 16; r++)
                p = fmaf(fmaxf(c3[mA][r], 0.f), mW4[mA * 32 + (r & 3) + 8 * (r >> 2) + 4 * h], p);
        p += __shfl_xor(p, 32, 64);
        int oidx = __shfl(efull, nB * 32 + lane, 64);
        if (lane < 32) out[oidx] = p + b4v;
    }
}

extern "C" void kernel_launch(void* const* d_in, const int* in_sizes, int n_in,
                              void* d_out, int out_size, void* d_ws, size_t ws_size,
                              hipStream_t stream) {
    const float* x   = (const float*)d_in[0];
    const int*   ei  = (const int*)d_in[1];
    const float* W1  = (const float*)d_in[2];
    const float* as1 = (const float*)d_in[3];
    const float* ad1 = (const float*)d_in[4];
    const float* b1  = (const float*)d_in[5];
    const float* W2  = (const float*)d_in[6];
    const float* as2 = (const float*)d_in[7];
    const float* ad2 = (const float*)d_in[8];
    const float* b2  = (const float*)d_in[9];
    const float* mW1 = (const float*)d_in[10];
    const float* mb1 = (const float*)d_in[11];
    const float* mW2 = (const float*)d_in[12];
    const float* mb2 = (const float*)d_in[13];
    const float* mW3 = (const float*)d_in[14];
    const float* mb3 = (const float*)d_in[15];
    const float* mW4 = (const float*)d_in[16];
    const float* mb4 = (const float*)d_in[17];
    float* out = (float*)d_out;
    const int* row = ei;             // src
    const int* col = ei + N_EDGES;   // dst

    char* w = (char*)d_ws;
    float* U     = (float*)w;                         // 12.8 MB, live k5b->k7
    float* V     = (float*)(w + 12800000);            // 12.8 MB, live k5b->k7
    float* h2    = (float*)(w + 25600000);            // 12.8 MB, live k4->k5a
    int*   ssrc  = (int*)(w + 38400000);              // 6.4 MB  (CSR order)
    int*   sdst  = (int*)(w + 44800000);              // 6.4 MB
    int*   eid   = (int*)(w + 51200000);              // 6.4 MB
    int*   eid2  = (int*)(w + 57600000);              // 6.4 MB  (2D order)
    int*   deg   = (int*)(w + 64000000);              // 0.2 MB
    int*   offp  = (int*)(w + 64200000);              // 0.2 MB + 4
    int*   cursor= (int*)(w + 64400064);              // 0.2 MB
    float* al_s2 = (float*)(w + 64600064);
    float* al_d2 = (float*)(w + 64800064);
    int*   bsum  = (int*)(w + 65000064);              // 1 KB
    float* qs    = (float*)(w + 65001088);            // 128 B
    float* qd    = (float*)(w + 65001216);            // 128 B
    unsigned short* W2th = (unsigned short*)(w + 65001344);
    unsigned short* W2tl = W2th + 4096;
    unsigned short* W3th = W2th + 8192;
    unsigned short* W3tl = W2th + 12288;              // ends 65,034,112
    int*   cnt   = (int*)(w + 65034112);              // 7*6250*4 = 175 KB
    int*   basep = (int*)(w + 65209112 + 8);          // 175 KB  (aligned enough: /4)
    // overlays:
    float* accx  = U;                                 // live k3->k4 (inside U)
    float* denb  = (float*)(w + 6400000);             // live k3->k4
    float* al_s1 = (float*)(w + 6800000);             // live k1->k3
    float* al_d1 = (float*)(w + 7200000);             // live k1->k3
    float* out2  = U;                                 // live k5a->k5b (in-place to U)
    int*   s2src = (int*)(w + 25600000);              // overlays h2 (dead after k5a)
    int*   s2dst = (int*)(w + 32000000);

    hipMemsetAsync(deg, 0, N_NODES * sizeof(int), stream);
    k_qprep<<<1, 64, 0, stream>>>(W1, as1, ad1, qs, qd);
    k_wprep<<<64, 64, 0, stream>>>(mW2, mW3, W2th, W2tl, W3th, W3tl);
    k1n<<<(N_NODES + 255) / 256, 256, 0, stream>>>(x, qs, qd, al_s1, al_d1);
    k_hist<<<(N_EDGES + 255) / 256, 256, 0, stream>>>(col, deg);
    k_scan1<<<(N_NODES + SCAN_B - 1) / SCAN_B, SCAN_B, 0, stream>>>(deg, offp, bsum);
    k_scan2<<<1, SCAN_B, 0, stream>>>(bsum, (N_NODES + SCAN_B - 1) / SCAN_B);
    k_scan3<<<(N_NODES + SCAN_B - 1) / SCAN_B, SCAN_B, 0, stream>>>(offp, bsum, cursor);
    k_scatter3<<<(N_EDGES + 255) / 256, 256, 0, stream>>>(row, col, cursor, ssrc, sdst, eid);
    p_hist<<<NBLK, 256, 0, stream>>>(ssrc, cnt);
    p_scan<<<1, 512, 0, stream>>>(cnt, basep);
    k3n<<<N_NODES / 8, 256, 0, stream>>>(x, al_s1, al_d1, offp, ssrc, accx, denb);
    k4n<<<N_NODES / 4, 256, 0, stream>>>(accx, denb, W1, b1, W2, as2, ad2, h2, al_s2, al_d2);
    k5a<<<N_NODES, 64, 0, stream>>>(h2, al_s2, al_d2, b2, offp, ssrc, out2);
    p_scatter<<<NBLK, 256, 0, stream>>>(ssrc, sdst, eid, basep, s2src, s2dst, eid2);
    k5b<<<N_NODES / 4, 256, 0, stream>>>(out2, mW1, mb1, U, V);
    k7d<<<N_EDGES / 256, 256, 0, stream>>>(s2src, s2dst, eid2, U, V,
                                           W2th, W2tl, W3th, W3tl,
                                           mb2, mb3, mW4, mb4, out);
}

// Round 8
// 719.462 us; speedup vs baseline: 1.0405x; 1.0405x over previous
//
#include <hip/hip_runtime.h>
#include <hip/hip_bf16.h>
#include <math.h>

#define N_NODES 50000
#define N_EDGES 1600000
#define IN_DIM 16
#define HID 64
#define NBLK 6250          // N_EDGES / 256

typedef __attribute__((ext_vector_type(8))) short short8v;
typedef __attribute__((ext_vector_type(16))) float f32x16;

union U32x4S8 { unsigned u[4]; short8v s; };

__device__ __forceinline__ float lrelu(float v) { return v > 0.f ? v : 0.2f * v; }

__device__ __forceinline__ float wave_reduce_sum(float v) {
    #pragma unroll
    for (int off = 32; off > 0; off >>= 1) v += __shfl_down(v, off, 64);
    return v;
}

// online-softmax state update / merge
__device__ __forceinline__ void sm_upd(float& m, float& den, float& acc, float e, float v) {
    float n = fmaxf(m, e);
    float f = __expf(m - n), w = __expf(e - n);
    den = den * f + w;
    acc = acc * f + w * v;
    m = n;
}
__device__ __forceinline__ void sm_merge(float& m, float& den, float& acc,
                                         float m2, float den2, float acc2) {
    float mm = fmaxf(m, m2);
    float f1 = __expf(m - mm), f2 = __expf(m2 - mm);
    den = den * f1 + den2 * f2;
    acc = acc * f1 + acc2 * f2;
    m = mm;
}

__device__ __forceinline__ unsigned pk_bf16(float a, float b) {
    unsigned ua = (unsigned)__bfloat16_as_ushort(__float2bfloat16(a));
    unsigned ub = (unsigned)__bfloat16_as_ushort(__float2bfloat16(b));
    return ua | (ub << 16);
}
__device__ __forceinline__ void hilo2(float f0, float f1, unsigned& hw, unsigned& lw) {
    __hip_bfloat16 h0 = __float2bfloat16(f0), h1 = __float2bfloat16(f1);
    float r0 = __bfloat162float(h0), r1 = __bfloat162float(h1);
    hw = (unsigned)__bfloat16_as_ushort(h0) | ((unsigned)__bfloat16_as_ushort(h1) << 16);
    lw = pk_bf16(f0 - r0, f1 - r1);
}

// qs[i][h] = sum_c W1[i, h*64+c] * as1[h,c]  (and qd with ad1)
__global__ void k_qprep(const float* __restrict__ W1, const float* __restrict__ as1,
                        const float* __restrict__ ad1, float* __restrict__ qs, float* __restrict__ qd) {
    int t = threadIdx.x;
    if (t < 32) {
        int i = t >> 1, h = t & 1;
        float s = 0.f, d = 0.f;
        for (int c = 0; c < 64; c++) {
            float w = W1[i * 128 + h * 64 + c];
            s = fmaf(w, as1[h * 64 + c], s);
            d = fmaf(w, ad1[h * 64 + c], d);
        }
        qs[i * 2 + h] = s; qd[i * 2 + h] = d;
    }
}

__global__ void k1n(const float* __restrict__ x, const float* __restrict__ qs,
                    const float* __restrict__ qd, float* __restrict__ al_s, float* __restrict__ al_d) {
    int n = blockIdx.x * 256 + threadIdx.x;
    if (n >= N_NODES) return;
    float s0 = 0.f, s1 = 0.f, d0 = 0.f, d1 = 0.f;
    #pragma unroll
    for (int i = 0; i < IN_DIM; i++) {
        float xv = x[n * IN_DIM + i];
        s0 = fmaf(xv, qs[i * 2 + 0], s0);
        s1 = fmaf(xv, qs[i * 2 + 1], s1);
        d0 = fmaf(xv, qd[i * 2 + 0], d0);
        d1 = fmaf(xv, qd[i * 2 + 1], d1);
    }
    al_s[n * 2 + 0] = s0; al_s[n * 2 + 1] = s1;
    al_d[n * 2 + 0] = d0; al_d[n * 2 + 1] = d1;
}

// CSR build
__global__ void k_hist(const int* __restrict__ dst, int* __restrict__ deg) {
    int e = blockIdx.x * blockDim.x + threadIdx.x;
    if (e < N_EDGES) atomicAdd(&deg[dst[e]], 1);
}

#define SCAN_B 256
__global__ void k_scan1(const int* __restrict__ deg, int* __restrict__ off, int* __restrict__ bsum) {
    __shared__ int sh[SCAN_B];
    int gid = blockIdx.x * SCAN_B + threadIdx.x;
    int v = (gid < N_NODES) ? deg[gid] : 0;
    sh[threadIdx.x] = v;
    __syncthreads();
    for (int o = 1; o < SCAN_B; o <<= 1) {
        int t = (threadIdx.x >= o) ? sh[threadIdx.x - o] : 0;
        __syncthreads();
        sh[threadIdx.x] += t;
        __syncthreads();
    }
    int incl = sh[threadIdx.x];
    if (gid < N_NODES) off[gid] = incl - v;
    if (threadIdx.x == SCAN_B - 1) bsum[blockIdx.x] = incl;
}
__global__ void k_scan2(int* __restrict__ bsum, int nblocks) {
    __shared__ int sh[SCAN_B];
    int v = (threadIdx.x < nblocks) ? bsum[threadIdx.x] : 0;
    sh[threadIdx.x] = v;
    __syncthreads();
    for (int o = 1; o < SCAN_B; o <<= 1) {
        int t = (threadIdx.x >= o) ? sh[threadIdx.x - o] : 0;
        __syncthreads();
        sh[threadIdx.x] += t;
        __syncthreads();
    }
    if (threadIdx.x < nblocks) bsum[threadIdx.x] = sh[threadIdx.x] - v;
}
__global__ void k_scan3(int* __restrict__ off, const int* __restrict__ bsum, int* __restrict__ cursor) {
    int gid = blockIdx.x * SCAN_B + threadIdx.x;
    if (gid < N_NODES) {
        int o = off[gid] + bsum[blockIdx.x];
        off[gid] = o;
        cursor[gid] = o;
    }
    if (gid == 0) off[N_NODES] = N_EDGES;
}
__global__ void k_scatter3(const int* __restrict__ src, const int* __restrict__ dst,
                           int* __restrict__ cursor, int* __restrict__ ssrc,
                           int* __restrict__ sdst, int* __restrict__ eid) {
    int e = blockIdx.x * blockDim.x + threadIdx.x;
    if (e < N_EDGES) {
        int d = dst[e];
        int pos = atomicAdd(&cursor[d], 1);
        ssrc[pos] = src[e];
        sdst[pos] = d;
        eid[pos] = e;
    }
}

// ---- stable 7-bucket partition by src>>13 (keeps dst order within bucket) ----
__global__ __launch_bounds__(256) void p_hist(const int* __restrict__ ssrc, int* __restrict__ cnt) {
    __shared__ int c[7];
    if (threadIdx.x < 7) c[threadIdx.x] = 0;
    __syncthreads();
    int i = blockIdx.x * 256 + threadIdx.x;
    atomicAdd(&c[ssrc[i] >> 13], 1);
    __syncthreads();
    if (threadIdx.x < 7) cnt[threadIdx.x * NBLK + blockIdx.x] = c[threadIdx.x];
}

// generalized block scan: exclusive within block, block totals to bsum
__global__ void g_scan1(const int* __restrict__ in, int* __restrict__ out,
                        int* __restrict__ bsum, int n) {
    __shared__ int sh[SCAN_B];
    int gid = blockIdx.x * SCAN_B + threadIdx.x;
    int v = (gid < n) ? in[gid] : 0;
    sh[threadIdx.x] = v;
    __syncthreads();
    for (int o = 1; o < SCAN_B; o <<= 1) {
        int t = (threadIdx.x >= o) ? sh[threadIdx.x - o] : 0;
        __syncthreads();
        sh[threadIdx.x] += t;
        __syncthreads();
    }
    int incl = sh[threadIdx.x];
    if (gid < n) out[gid] = incl - v;
    if (threadIdx.x == SCAN_B - 1) bsum[blockIdx.x] = incl;
}
__global__ void g_add(int* __restrict__ out, const int* __restrict__ bsum, int n) {
    int gid = blockIdx.x * SCAN_B + threadIdx.x;
    if (gid < n) out[gid] += bsum[blockIdx.x];
}

__global__ __launch_bounds__(256) void p_scatter(
    const int* __restrict__ ssrc, const int* __restrict__ sdst, const int* __restrict__ eid,
    const int* __restrict__ basep, int* __restrict__ s2s, int* __restrict__ s2d, int* __restrict__ e2) {
    __shared__ int wcnt[4][7];
    int wid = threadIdx.x >> 6, lane = threadIdx.x & 63;
    int i = blockIdx.x * 256 + threadIdx.x;
    int s = ssrc[i], d = sdst[i], e = eid[i];
    int k = s >> 13;
    int rank = 0;
    #pragma unroll
    for (int kk = 0; kk < 7; kk++) {
        unsigned long long m = __ballot(k == kk);
        if (k == kk) rank = __popcll(m & ((1ull << lane) - 1ull));
        if (lane == kk) wcnt[wid][kk] = __popcll(m);
    }
    __syncthreads();
    int prev = 0;
    #pragma unroll
    for (int w = 0; w < 4; w++) if (w < wid) prev += wcnt[w][k];
    int pos = basep[k * NBLK + blockIdx.x] + prev + rank;
    s2s[pos] = s; s2d[pos] = d; e2[pos] = e;
}

// K3n: layer-1 aggregation in x-space, 8 independent online-softmax chains.
__global__ void k3n(const float* __restrict__ x, const float* __restrict__ als,
                    const float* __restrict__ ald, const int* __restrict__ off,
                    const int* __restrict__ ssrc, float* __restrict__ accx,
                    float* __restrict__ denb) {
    int wid = threadIdx.x >> 6, lane = threadIdx.x & 63;
    int half = lane >> 5, sub = lane & 31, head = sub >> 4, ch = sub & 15;
    int d = blockIdx.x * 8 + wid * 2 + half;
    if (d >= N_NODES) return;
    int beg = off[d], end = off[d + 1];
    float adv = ald[d * 2 + head];
    float m[8], den[8], acc[8];
    m[0] = lrelu(als[d * 2 + head] + adv); den[0] = 1.f; acc[0] = x[d * IN_DIM + ch];
    #pragma unroll
    for (int t = 1; t < 8; t++) { m[t] = -1e30f; den[t] = 0.f; acc[t] = 0.f; }
    int i = beg;
    for (; i + 7 < end; i += 8) {
        int sv[8]; float ev[8], xv[8];
        #pragma unroll
        for (int t = 0; t < 8; t++) sv[t] = ssrc[i + t];
        #pragma unroll
        for (int t = 0; t < 8; t++) ev[t] = lrelu(als[sv[t] * 2 + head] + adv);
        #pragma unroll
        for (int t = 0; t < 8; t++) xv[t] = x[sv[t] * IN_DIM + ch];
        #pragma unroll
        for (int t = 0; t < 8; t++) sm_upd(m[t], den[t], acc[t], ev[t], xv[t]);
    }
    for (; i < end; i++) {
        int s = ssrc[i];
        sm_upd(m[0], den[0], acc[0], lrelu(als[s * 2 + head] + adv), x[s * IN_DIM + ch]);
    }
    #pragma unroll
    for (int t = 4; t < 8; t++) sm_merge(m[t - 4], den[t - 4], acc[t - 4], m[t], den[t], acc[t]);
    sm_merge(m[0], den[0], acc[0], m[1], den[1], acc[1]);
    sm_merge(m[2], den[2], acc[2], m[3], den[3], acc[3]);
    sm_merge(m[0], den[0], acc[0], m[2], den[2], acc[2]);
    accx[d * 32 + sub] = acc[0];
    if ((sub & 15) == 0) denb[d * 2 + head] = den[0];
}

// K4n: fused out1-expand then @ W2 -> h2, al_s2/al_d2.
__global__ __launch_bounds__(256) void k4n(
    const float* __restrict__ accx, const float* __restrict__ denb,
    const float* __restrict__ W1, const float* __restrict__ b1,
    const float* __restrict__ W2, const float* __restrict__ as2, const float* __restrict__ ad2,
    float* __restrict__ h2, float* __restrict__ al_s, float* __restrict__ al_d) {
    __shared__ float W1s[16 * 128];
    __shared__ float W2s[128 * 64];
    __shared__ float st[4][160];
    for (int t = threadIdx.x; t < 16 * 128; t += 256) W1s[t] = W1[t];
    for (int t = threadIdx.x; t < 128 * 64; t += 256) W2s[t] = W2[t];
    __syncthreads();
    int wid = threadIdx.x >> 6, lane = threadIdx.x & 63;
    int n = blockIdx.x * 4 + wid;
    if (n >= N_NODES) return;
    if (lane < 32) st[wid][lane] = accx[n * 32 + lane];
    float den0 = denb[n * 2], den1 = denb[n * 2 + 1];
    float ta = 0.f, tb = 0.f;
    #pragma unroll
    for (int i = 0; i < 16; i++) {
        ta = fmaf(st[wid][i],      W1s[i * 128 + lane],      ta);
        tb = fmaf(st[wid][16 + i], W1s[i * 128 + 64 + lane], tb);
    }
    ta = fmaxf(ta / den0 + b1[lane], 0.f);
    tb = fmaxf(tb / den1 + b1[64 + lane], 0.f);
    st[wid][32 + lane] = ta;
    st[wid][96 + lane] = tb;
    float acc = 0.f;
    #pragma unroll 8
    for (int k = 0; k < 128; k++) acc = fmaf(st[wid][32 + k], W2s[k * 64 + lane], acc);
    h2[n * 64 + lane] = acc;
    float ps = wave_reduce_sum(acc * as2[lane]);
    float pd = wave_reduce_sum(acc * ad2[lane]);
    if (lane == 0) { al_s[n] = ps; al_d[n] = pd; }
}

// K5a: layer-2 aggregation, one dst per 64-thread block, 8 chains, no LDS.
__global__ __launch_bounds__(64) void k5a(
    const float* __restrict__ h2, const float* __restrict__ als, const float* __restrict__ ald,
    const float* __restrict__ b2, const int* __restrict__ off, const int* __restrict__ ssrc,
    float* __restrict__ out2) {
    int d = blockIdx.x;
    int lane = threadIdx.x;
    int beg = off[d], end = off[d + 1];
    float adv = ald[d];
    float m[8], den[8], acc[8];
    m[0] = lrelu(als[d] + adv); den[0] = 1.f; acc[0] = h2[d * 64 + lane];
    #pragma unroll
    for (int t = 1; t < 8; t++) { m[t] = -1e30f; den[t] = 0.f; acc[t] = 0.f; }
    int i = beg;
    for (; i + 7 < end; i += 8) {
        int sv[8]; float ev[8], vv[8];
        #pragma unroll
        for (int t = 0; t < 8; t++) sv[t] = ssrc[i + t];
        #pragma unroll
        for (int t = 0; t < 8; t++) ev[t] = lrelu(als[sv[t]] + adv);
        #pragma unroll
        for (int t = 0; t < 8; t++) vv[t] = h2[sv[t] * 64 + lane];
        #pragma unroll
        for (int t = 0; t < 8; t++) sm_upd(m[t], den[t], acc[t], ev[t], vv[t]);
    }
    for (; i < end; i++) {
        int s = ssrc[i];
        sm_upd(m[0], den[0], acc[0], lrelu(als[s] + adv), h2[s * 64 + lane]);
    }
    #pragma unroll
    for (int t = 4; t < 8; t++) sm_merge(m[t - 4], den[t - 4], acc[t - 4], m[t], den[t], acc[t]);
    sm_merge(m[0], den[0], acc[0], m[1], den[1], acc[1]);
    sm_merge(m[2], den[2], acc[2], m[3], den[3], acc[3]);
    sm_merge(m[0], den[0], acc[0], m[2], den[2], acc[2]);
    out2[d * 64 + lane] = fmaxf(acc[0] / den[0] + b2[lane], 0.f);
}

// K5b: U = out2 @ mW1[0:64,:] + mb1, V = out2 @ mW1[64:128,:].
__global__ __launch_bounds__(256) void k5b(const float* out2, const float* __restrict__ mW1,
                                           const float* __restrict__ mb1,
                                           float* U, float* __restrict__ V) {
    __shared__ float Ws[128 * 64];
    __shared__ float o2s[4][64];
    for (int t = threadIdx.x; t < 128 * 64; t += 256) Ws[t] = mW1[t];
    __syncthreads();
    int wid = threadIdx.x >> 6, lane = threadIdx.x & 63;
    int n = blockIdx.x * 4 + wid;
    if (n >= N_NODES) return;
    o2s[wid][lane] = out2[n * 64 + lane];
    float au = mb1[lane], av = 0.f;
    #pragma unroll 8
    for (int k = 0; k < 64; k++) {
        float ov = o2s[wid][k];
        au = fmaf(ov, Ws[k * 64 + lane], au);
        av = fmaf(ov, Ws[(64 + k) * 64 + lane], av);
    }
    U[n * 64 + lane] = au;
    V[n * 64 + lane] = av;
}

// weight prep: bf16 hi/lo split of mW2^T, mW3^T
__global__ void k_wprep(const float* __restrict__ mW2, const float* __restrict__ mW3,
                        unsigned short* __restrict__ W2th, unsigned short* __restrict__ W2tl,
                        unsigned short* __restrict__ W3th, unsigned short* __restrict__ W3tl) {
    int b = blockIdx.x, t = threadIdx.x;
    float w2 = mW2[t * 64 + b];
    __hip_bfloat16 h2 = __float2bfloat16(w2);
    W2th[b * 64 + t] = __bfloat16_as_ushort(h2);
    W2tl[b * 64 + t] = __bfloat16_as_ushort(__float2bfloat16(w2 - __bfloat162float(h2)));
    float w3 = mW3[t * 64 + b];
    __hip_bfloat16 h3 = __float2bfloat16(w3);
    W3th[b * 64 + t] = __bfloat16_as_ushort(h3);
    W3tl[b * 64 + t] = __bfloat16_as_ushort(__float2bfloat16(w3 - __bfloat162float(h3)));
}

// K7e: edge MLP via MFMA, 32 edges per wave (halved tile -> lower VGPR -> 2x occupancy).
// B3 fragments built fully before layer 3 so c2 and c3 are never co-live.
__global__ __launch_bounds__(256) void k7e(
    const int* __restrict__ s2s, const int* __restrict__ s2d, const int* __restrict__ e2,
    const float* __restrict__ Ub, const float* __restrict__ Vb,
    const unsigned short* __restrict__ W2th, const unsigned short* __restrict__ W2tl,
    const unsigned short* __restrict__ W3th, const unsigned short* __restrict__ W3tl,
    const float* __restrict__ mb2, const float* __restrict__ mb3,
    const float* __restrict__ mW4, const float* __restrict__ mb4,
    float* __restrict__ out)
{
    const int wid = threadIdx.x >> 6, lane = threadIdx.x & 63;
    const int tbase = blockIdx.x * 128 + wid * 32;
    const int l31 = lane & 31;
    const int h = lane >> 5;
    const int ksub = h * 8;

    int rA = s2s[tbase + l31];
    int cA = s2d[tbase + l31];
    const float* urow = Ub + rA * 64 + ksub;
    const float* vrow = Vb + cA * 64 + ksub;

    // ---- layer 2 ----
    f32x16 c2[2];
    #pragma unroll
    for (int mA = 0; mA < 2; mA++)
        #pragma unroll
        for (int r = 0; r < 16; r++)
            c2[mA][r] = mb2[mA * 32 + (r & 3) + 8 * (r >> 2) + 4 * h];

    #pragma unroll
    for (int kb = 0; kb < 4; kb++) {
        float4 u0 = *(const float4*)(urow + kb * 16);
        float4 u1 = *(const float4*)(urow + kb * 16 + 4);
        float4 v0 = *(const float4*)(vrow + kb * 16);
        float4 v1 = *(const float4*)(vrow + kb * 16 + 4);
        float z[8];
        z[0] = fmaxf(u0.x + v0.x, 0.f); z[1] = fmaxf(u0.y + v0.y, 0.f);
        z[2] = fmaxf(u0.z + v0.z, 0.f); z[3] = fmaxf(u0.w + v0.w, 0.f);
        z[4] = fmaxf(u1.x + v1.x, 0.f); z[5] = fmaxf(u1.y + v1.y, 0.f);
        z[6] = fmaxf(u1.z + v1.z, 0.f); z[7] = fmaxf(u1.w + v1.w, 0.f);
        U32x4S8 bh, bl;
        #pragma unroll
        for (int q = 0; q < 4; q++) hilo2(z[2 * q], z[2 * q + 1], bh.u[q], bl.u[q]);
        #pragma unroll
        for (int mA = 0; mA < 2; mA++) {
            const int wrow = (mA * 32 + l31) * 64 + kb * 16 + ksub;
            short8v ah = *(const short8v*)(W2th + wrow);
            short8v al = *(const short8v*)(W2tl + wrow);
            c2[mA] = __builtin_amdgcn_mfma_f32_32x32x16_bf16(ah, bh.s, c2[mA], 0, 0, 0);
            c2[mA] = __builtin_amdgcn_mfma_f32_32x32x16_bf16(al, bh.s, c2[mA], 0, 0, 0);
            c2[mA] = __builtin_amdgcn_mfma_f32_32x32x16_bf16(ah, bl.s, c2[mA], 0, 0, 0);
            c2[mA] = __builtin_amdgcn_mfma_f32_32x32x16_bf16(al, bl.s, c2[mA], 0, 0, 0);
        }
    }

    // ---- refragment relu(c2) -> B3 (c2 dies here) ----
    unsigned B3h[4][4], B3l[4][4];
    #pragma unroll
    for (int kbp = 0; kbp < 4; kbp++) {
        const int mAs = kbp >> 1, kbl = kbp & 1;
        float e[8];
        #pragma unroll
        for (int b = 0; b < 4; b++) {
            float u = fmaxf(c2[mAs][8 * kbl + b], 0.f);
            float v = fmaxf(c2[mAs][8 * kbl + 4 + b], 0.f);
            float su = __shfl_xor(u, 32, 64);
            float sv = __shfl_xor(v, 32, 64);
            e[b]     = h ? sv : u;
            e[4 + b] = h ? v : su;
        }
        #pragma unroll
        for (int q = 0; q < 4; q++) hilo2(e[2 * q], e[2 * q + 1], B3h[kbp][q], B3l[kbp][q]);
    }

    // ---- layer 3 ----
    f32x16 c3[2];
    #pragma unroll
    for (int mA = 0; mA < 2; mA++)
        #pragma unroll
        for (int r = 0; r < 16; r++)
            c3[mA][r] = mb3[mA * 32 + (r & 3) + 8 * (r >> 2) + 4 * h];

    #pragma unroll
    for (int kbp = 0; kbp < 4; kbp++) {
        U32x4S8 bh, bl;
        #pragma unroll
        for (int q = 0; q < 4; q++) { bh.u[q] = B3h[kbp][q]; bl.u[q] = B3l[kbp][q]; }
        #pragma unroll
        for (int mA = 0; mA < 2; mA++) {
            const int wrow = (mA * 32 + l31) * 64 + kbp * 16 + ksub;
            short8v ah = *(const short8v*)(W3th + wrow);
            short8v al = *(const short8v*)(W3tl + wrow);
            c3[mA] = __builtin_amdgcn_mfma_f32_32x32x16_bf16(ah, bh.s, c3[mA], 0, 0, 0);
            c3[mA] = __builtin_amdgcn_mfma_f32_32x32x16_bf16(al, bh.s, c3[mA], 0, 0, 0);
            c3[mA] = __builtin_amdgcn_mfma_f32_32x32x16_bf16(ah, bl.s, c3[mA], 0, 0, 0);
            c3[mA] = __builtin_amdgcn_mfma_f32_32x32x16_bf16(al, bl.s, c3[mA], 0, 0, 0);
        }
    }

    float p = 0.f;
    #pragma unroll
    for (int mA = 0; mA < 2; mA++)
        #pragma unroll
        for (int r = 0; r < 16; r++)
            p = fmaf(fmaxf(c3[mA][r], 0.f), mW4[mA * 32 + (r & 3) + 8 * (r >> 2) + 4 * h], p);
    p += __shfl_xor(p, 32, 64);
    int eA = e2[tbase + l31];
    if (lane < 32) out[eA] = p + mb4[0];
}

extern "C" void kernel_launch(void* const* d_in, const int* in_sizes, int n_in,
                              void* d_out, int out_size, void* d_ws, size_t ws_size,
                              hipStream_t stream) {
    const float* x   = (const float*)d_in[0];
    const int*   ei  = (const int*)d_in[1];
    const float* W1  = (const float*)d_in[2];
    const float* as1 = (const float*)d_in[3];
    const float* ad1 = (const float*)d_in[4];
    const float* b1  = (const float*)d_in[5];
    const float* W2  = (const float*)d_in[6];
    const float* as2 = (const float*)d_in[7];
    const float* ad2 = (const float*)d_in[8];
    const float* b2  = (const float*)d_in[9];
    const float* mW1 = (const float*)d_in[10];
    const float* mb1 = (const float*)d_in[11];
    const float* mW2 = (const float*)d_in[12];
    const float* mb2 = (const float*)d_in[13];
    const float* mW3 = (const float*)d_in[14];
    const float* mb3 = (const float*)d_in[15];
    const float* mW4 = (const float*)d_in[16];
    const float* mb4 = (const float*)d_in[17];
    float* out = (float*)d_out;
    const int* row = ei;             // src
    const int* col = ei + N_EDGES;   // dst

    char* w = (char*)d_ws;
    float* U     = (float*)w;                         // 12.8 MB, live k5b->k7
    float* V     = (float*)(w + 12800000);            // 12.8 MB, live k5b->k7
    float* h2    = (float*)(w + 25600000);            // 12.8 MB, live k4->k5a
    int*   ssrc  = (int*)(w + 38400000);              // 6.4 MB  (CSR order)
    int*   sdst  = (int*)(w + 44800000);              // 6.4 MB
    int*   eid   = (int*)(w + 51200000);              // 6.4 MB
    int*   eid2  = (int*)(w + 57600000);              // 6.4 MB  (2D order)
    int*   deg   = (int*)(w + 64000000);              // 0.2 MB
    int*   offp  = (int*)(w + 64200000);              // 0.2 MB + 4
    int*   cursor= (int*)(w + 64400064);              // 0.2 MB
    float* al_s2 = (float*)(w + 64600064);
    float* al_d2 = (float*)(w + 64800064);
    int*   bsum  = (int*)(w + 65000064);              // 1 KB
    float* qs    = (float*)(w + 65001088);            // 128 B
    float* qd    = (float*)(w + 65001216);            // 128 B
    unsigned short* W2th = (unsigned short*)(w + 65001344);
    unsigned short* W2tl = W2th + 4096;
    unsigned short* W3th = W2th + 8192;
    unsigned short* W3tl = W2th + 12288;              // ends 65,034,112
    int*   cnt   = (int*)(w + 65034112);              // 7*6250*4 = 175 KB
    int*   basep = (int*)(w + 65209120);              // 175 KB
    // overlays:
    float* accx  = U;                                 // live k3->k4 (inside U)
    float* denb  = (float*)(w + 6400000);             // live k3->k4
    float* al_s1 = (float*)(w + 6800000);             // live k1->k3
    float* al_d1 = (float*)(w + 7200000);             // live k1->k3
    float* out2  = U;                                 // live k5a->k5b (in-place to U)
    int*   s2src = (int*)(w + 25600000);              // overlays h2 (dead after k5a)
    int*   s2dst = (int*)(w + 32000000);

    hipMemsetAsync(deg, 0, N_NODES * sizeof(int), stream);
    k_qprep<<<1, 64, 0, stream>>>(W1, as1, ad1, qs, qd);
    k_wprep<<<64, 64, 0, stream>>>(mW2, mW3, W2th, W2tl, W3th, W3tl);
    k1n<<<(N_NODES + 255) / 256, 256, 0, stream>>>(x, qs, qd, al_s1, al_d1);
    k_hist<<<(N_EDGES + 255) / 256, 256, 0, stream>>>(col, deg);
    k_scan1<<<(N_NODES + SCAN_B - 1) / SCAN_B, SCAN_B, 0, stream>>>(deg, offp, bsum);
    k_scan2<<<1, SCAN_B, 0, stream>>>(bsum, (N_NODES + SCAN_B - 1) / SCAN_B);
    k_scan3<<<(N_NODES + SCAN_B - 1) / SCAN_B, SCAN_B, 0, stream>>>(offp, bsum, cursor);
    k_scatter3<<<(N_EDGES + 255) / 256, 256, 0, stream>>>(row, col, cursor, ssrc, sdst, eid);
    // bucket partition offsets: 3-level parallel scan over cnt[7][NBLK]
    p_hist<<<NBLK, 256, 0, stream>>>(ssrc, cnt);
    {
        int n = 7 * NBLK;                             // 43750
        int nb = (n + SCAN_B - 1) / SCAN_B;           // 171
        g_scan1<<<nb, SCAN_B, 0, stream>>>(cnt, basep, bsum, n);
        k_scan2<<<1, SCAN_B, 0, stream>>>(bsum, nb);
        g_add<<<nb, SCAN_B, 0, stream>>>(basep, bsum, n);
    }
    k3n<<<N_NODES / 8, 256, 0, stream>>>(x, al_s1, al_d1, offp, ssrc, accx, denb);
    k4n<<<N_NODES / 4, 256, 0, stream>>>(accx, denb, W1, b1, W2, as2, ad2, h2, al_s2, al_d2);
    k5a<<<N_NODES, 64, 0, stream>>>(h2, al_s2, al_d2, b2, offp, ssrc, out2);
    p_scatter<<<NBLK, 256, 0, stream>>>(ssrc, sdst, eid, basep, s2src, s2dst, eid2);
    k5b<<<N_NODES / 4, 256, 0, stream>>>(out2, mW1, mb1, U, V);
    k7e<<<N_EDGES / 128, 256, 0, stream>>>(s2src, s2dst, eid2, U, V,
                                           W2th, W2tl, W3th, W3tl,
                                           mb2, mb3, mW4, mb4, out);
}

// Round 9
// 545.958 us; speedup vs baseline: 1.3711x; 1.3178x over previous
//
#include <hip/hip_runtime.h>
#include <hip/hip_bf16.h>
#include <hip/hip_fp16.h>
#include <math.h>

#define N_NODES 50000
#define N_EDGES 1600000
#define IN_DIM 16
#define HID 64
#define NBLK 6250          // N_EDGES / 256

typedef __attribute__((ext_vector_type(8))) short short8v;
typedef __attribute__((ext_vector_type(16))) float f32x16;

union U32x4S8 { unsigned u[4]; short8v s; };

__device__ __forceinline__ float lrelu(float v) { return v > 0.f ? v : 0.2f * v; }

__device__ __forceinline__ float wave_reduce_sum(float v) {
    #pragma unroll
    for (int off = 32; off > 0; off >>= 1) v += __shfl_down(v, off, 64);
    return v;
}

// online-softmax state update / merge
__device__ __forceinline__ void sm_upd(float& m, float& den, float& acc, float e, float v) {
    float n = fmaxf(m, e);
    float f = __expf(m - n), w = __expf(e - n);
    den = den * f + w;
    acc = acc * f + w * v;
    m = n;
}
__device__ __forceinline__ void sm_merge(float& m, float& den, float& acc,
                                         float m2, float den2, float acc2) {
    float mm = fmaxf(m, m2);
    float f1 = __expf(m - mm), f2 = __expf(m2 - mm);
    den = den * f1 + den2 * f2;
    acc = acc * f1 + acc2 * f2;
    m = mm;
}

__device__ __forceinline__ unsigned pk_bf16(float a, float b) {
    unsigned ua = (unsigned)__bfloat16_as_ushort(__float2bfloat16(a));
    unsigned ub = (unsigned)__bfloat16_as_ushort(__float2bfloat16(b));
    return ua | (ub << 16);
}
__device__ __forceinline__ void hilo2(float f0, float f1, unsigned& hw, unsigned& lw) {
    __hip_bfloat16 h0 = __float2bfloat16(f0), h1 = __float2bfloat16(f1);
    float r0 = __bfloat162float(h0), r1 = __bfloat162float(h1);
    hw = (unsigned)__bfloat16_as_ushort(h0) | ((unsigned)__bfloat16_as_ushort(h1) << 16);
    lw = pk_bf16(f0 - r0, f1 - r1);
}

// qs[i][h] = sum_c W1[i, h*64+c] * as1[h,c]  (and qd with ad1)
__global__ void k_qprep(const float* __restrict__ W1, const float* __restrict__ as1,
                        const float* __restrict__ ad1, float* __restrict__ qs, float* __restrict__ qd) {
    int t = threadIdx.x;
    if (t < 32) {
        int i = t >> 1, h = t & 1;
        float s = 0.f, d = 0.f;
        for (int c = 0; c < 64; c++) {
            float w = W1[i * 128 + h * 64 + c];
            s = fmaf(w, as1[h * 64 + c], s);
            d = fmaf(w, ad1[h * 64 + c], d);
        }
        qs[i * 2 + h] = s; qd[i * 2 + h] = d;
    }
}

__global__ void k1n(const float* __restrict__ x, const float* __restrict__ qs,
                    const float* __restrict__ qd, float* __restrict__ al_s, float* __restrict__ al_d) {
    int n = blockIdx.x * 256 + threadIdx.x;
    if (n >= N_NODES) return;
    float s0 = 0.f, s1 = 0.f, d0 = 0.f, d1 = 0.f;
    #pragma unroll
    for (int i = 0; i < IN_DIM; i++) {
        float xv = x[n * IN_DIM + i];
        s0 = fmaf(xv, qs[i * 2 + 0], s0);
        s1 = fmaf(xv, qs[i * 2 + 1], s1);
        d0 = fmaf(xv, qd[i * 2 + 0], d0);
        d1 = fmaf(xv, qd[i * 2 + 1], d1);
    }
    al_s[n * 2 + 0] = s0; al_s[n * 2 + 1] = s1;
    al_d[n * 2 + 0] = d0; al_d[n * 2 + 1] = d1;
}

// CSR build
__global__ void k_hist(const int* __restrict__ dst, int* __restrict__ deg) {
    int e = blockIdx.x * blockDim.x + threadIdx.x;
    if (e < N_EDGES) atomicAdd(&deg[dst[e]], 1);
}

#define SCAN_B 256
__global__ void k_scan1(const int* __restrict__ deg, int* __restrict__ off, int* __restrict__ bsum) {
    __shared__ int sh[SCAN_B];
    int gid = blockIdx.x * SCAN_B + threadIdx.x;
    int v = (gid < N_NODES) ? deg[gid] : 0;
    sh[threadIdx.x] = v;
    __syncthreads();
    for (int o = 1; o < SCAN_B; o <<= 1) {
        int t = (threadIdx.x >= o) ? sh[threadIdx.x - o] : 0;
        __syncthreads();
        sh[threadIdx.x] += t;
        __syncthreads();
    }
    int incl = sh[threadIdx.x];
    if (gid < N_NODES) off[gid] = incl - v;
    if (threadIdx.x == SCAN_B - 1) bsum[blockIdx.x] = incl;
}
__global__ void k_scan2(int* __restrict__ bsum, int nblocks) {
    __shared__ int sh[SCAN_B];
    int v = (threadIdx.x < nblocks) ? bsum[threadIdx.x] : 0;
    sh[threadIdx.x] = v;
    __syncthreads();
    for (int o = 1; o < SCAN_B; o <<= 1) {
        int t = (threadIdx.x >= o) ? sh[threadIdx.x - o] : 0;
        __syncthreads();
        sh[threadIdx.x] += t;
        __syncthreads();
    }
    if (threadIdx.x < nblocks) bsum[threadIdx.x] = sh[threadIdx.x] - v;
}
__global__ void k_scan3(int* __restrict__ off, const int* __restrict__ bsum, int* __restrict__ cursor) {
    int gid = blockIdx.x * SCAN_B + threadIdx.x;
    if (gid < N_NODES) {
        int o = off[gid] + bsum[blockIdx.x];
        off[gid] = o;
        cursor[gid] = o;
    }
    if (gid == 0) off[N_NODES] = N_EDGES;
}
// scatter edges into CSR order; pack (dst<<16 | src) into one u32
__global__ void k_scatter3(const int* __restrict__ src, const int* __restrict__ dst,
                           int* __restrict__ cursor, unsigned* __restrict__ ssd,
                           int* __restrict__ eid) {
    int e = blockIdx.x * blockDim.x + threadIdx.x;
    if (e < N_EDGES) {
        int d = dst[e];
        int pos = atomicAdd(&cursor[d], 1);
        ssd[pos] = ((unsigned)d << 16) | (unsigned)src[e];
        eid[pos] = e;
    }
}

// ---- stable 7-bucket partition by src>>13 (keeps dst order within bucket) ----
__global__ __launch_bounds__(256) void p_hist(const unsigned* __restrict__ ssd, int* __restrict__ cnt) {
    __shared__ int c[7];
    if (threadIdx.x < 7) c[threadIdx.x] = 0;
    __syncthreads();
    int i = blockIdx.x * 256 + threadIdx.x;
    atomicAdd(&c[(ssd[i] & 0xffff) >> 13], 1);
    __syncthreads();
    if (threadIdx.x < 7) cnt[threadIdx.x * NBLK + blockIdx.x] = c[threadIdx.x];
}

// generalized block scan: exclusive within block, block totals to bsum
__global__ void g_scan1(const int* __restrict__ in, int* __restrict__ out,
                        int* __restrict__ bsum, int n) {
    __shared__ int sh[SCAN_B];
    int gid = blockIdx.x * SCAN_B + threadIdx.x;
    int v = (gid < n) ? in[gid] : 0;
    sh[threadIdx.x] = v;
    __syncthreads();
    for (int o = 1; o < SCAN_B; o <<= 1) {
        int t = (threadIdx.x >= o) ? sh[threadIdx.x - o] : 0;
        __syncthreads();
        sh[threadIdx.x] += t;
        __syncthreads();
    }
    int incl = sh[threadIdx.x];
    if (gid < n) out[gid] = incl - v;
    if (threadIdx.x == SCAN_B - 1) bsum[blockIdx.x] = incl;
}
__global__ void g_add(int* __restrict__ out, const int* __restrict__ bsum, int n) {
    int gid = blockIdx.x * SCAN_B + threadIdx.x;
    if (gid < n) out[gid] += bsum[blockIdx.x];
}

__global__ __launch_bounds__(256) void p_scatter(
    const unsigned* __restrict__ ssd, const int* __restrict__ eid,
    const int* __restrict__ basep, unsigned* __restrict__ s2sd, int* __restrict__ e2) {
    __shared__ int wcnt[4][7];
    int wid = threadIdx.x >> 6, lane = threadIdx.x & 63;
    int i = blockIdx.x * 256 + threadIdx.x;
    unsigned v = ssd[i];
    int e = eid[i];
    int k = (v & 0xffff) >> 13;
    int rank = 0;
    #pragma unroll
    for (int kk = 0; kk < 7; kk++) {
        unsigned long long m = __ballot(k == kk);
        if (k == kk) rank = __popcll(m & ((1ull << lane) - 1ull));
        if (lane == kk) wcnt[wid][kk] = __popcll(m);
    }
    __syncthreads();
    int prev = 0;
    #pragma unroll
    for (int w = 0; w < 4; w++) if (w < wid) prev += wcnt[w][k];
    int pos = basep[k * NBLK + blockIdx.x] + prev + rank;
    s2sd[pos] = v; e2[pos] = e;
}

// K3n: layer-1 aggregation in x-space, 8 independent online-softmax chains.
__global__ void k3n(const float* __restrict__ x, const float* __restrict__ als,
                    const float* __restrict__ ald, const int* __restrict__ off,
                    const unsigned* __restrict__ ssd, float* __restrict__ accx,
                    float* __restrict__ denb) {
    int wid = threadIdx.x >> 6, lane = threadIdx.x & 63;
    int half = lane >> 5, sub = lane & 31, head = sub >> 4, ch = sub & 15;
    int d = blockIdx.x * 8 + wid * 2 + half;
    if (d >= N_NODES) return;
    int beg = off[d], end = off[d + 1];
    float adv = ald[d * 2 + head];
    float m[8], den[8], acc[8];
    m[0] = lrelu(als[d * 2 + head] + adv); den[0] = 1.f; acc[0] = x[d * IN_DIM + ch];
    #pragma unroll
    for (int t = 1; t < 8; t++) { m[t] = -1e30f; den[t] = 0.f; acc[t] = 0.f; }
    int i = beg;
    for (; i + 7 < end; i += 8) {
        int sv[8]; float ev[8], xv[8];
        #pragma unroll
        for (int t = 0; t < 8; t++) sv[t] = (int)(ssd[i + t] & 0xffffu);
        #pragma unroll
        for (int t = 0; t < 8; t++) ev[t] = lrelu(als[sv[t] * 2 + head] + adv);
        #pragma unroll
        for (int t = 0; t < 8; t++) xv[t] = x[sv[t] * IN_DIM + ch];
        #pragma unroll
        for (int t = 0; t < 8; t++) sm_upd(m[t], den[t], acc[t], ev[t], xv[t]);
    }
    for (; i < end; i++) {
        int s = (int)(ssd[i] & 0xffffu);
        sm_upd(m[0], den[0], acc[0], lrelu(als[s * 2 + head] + adv), x[s * IN_DIM + ch]);
    }
    #pragma unroll
    for (int t = 4; t < 8; t++) sm_merge(m[t - 4], den[t - 4], acc[t - 4], m[t], den[t], acc[t]);
    sm_merge(m[0], den[0], acc[0], m[1], den[1], acc[1]);
    sm_merge(m[2], den[2], acc[2], m[3], den[3], acc[3]);
    sm_merge(m[0], den[0], acc[0], m[2], den[2], acc[2]);
    accx[d * 32 + sub] = acc[0];
    if ((sub & 15) == 0) denb[d * 2 + head] = den[0];
}

// K4n: fused out1-expand then @ W2 -> h2 (f16), al_s2/al_d2.
__global__ __launch_bounds__(256) void k4n(
    const float* __restrict__ accx, const float* __restrict__ denb,
    const float* __restrict__ W1, const float* __restrict__ b1,
    const float* __restrict__ W2, const float* __restrict__ as2, const float* __restrict__ ad2,
    __half* __restrict__ h2h, float* __restrict__ al_s, float* __restrict__ al_d) {
    __shared__ float W1s[16 * 128];
    __shared__ float W2s[128 * 64];
    __shared__ float st[4][160];
    for (int t = threadIdx.x; t < 16 * 128; t += 256) W1s[t] = W1[t];
    for (int t = threadIdx.x; t < 128 * 64; t += 256) W2s[t] = W2[t];
    __syncthreads();
    int wid = threadIdx.x >> 6, lane = threadIdx.x & 63;
    int n = blockIdx.x * 4 + wid;
    if (n >= N_NODES) return;
    if (lane < 32) st[wid][lane] = accx[n * 32 + lane];
    float den0 = denb[n * 2], den1 = denb[n * 2 + 1];
    float ta = 0.f, tb = 0.f;
    #pragma unroll
    for (int i = 0; i < 16; i++) {
        ta = fmaf(st[wid][i],      W1s[i * 128 + lane],      ta);
        tb = fmaf(st[wid][16 + i], W1s[i * 128 + 64 + lane], tb);
    }
    ta = fmaxf(ta / den0 + b1[lane], 0.f);
    tb = fmaxf(tb / den1 + b1[64 + lane], 0.f);
    st[wid][32 + lane] = ta;
    st[wid][96 + lane] = tb;
    float acc = 0.f;
    #pragma unroll 8
    for (int k = 0; k < 128; k++) acc = fmaf(st[wid][32 + k], W2s[k * 64 + lane], acc);
    h2h[n * 64 + lane] = __float2half(acc);
    float ps = wave_reduce_sum(acc * as2[lane]);
    float pd = wave_reduce_sum(acc * ad2[lane]);
    if (lane == 0) { al_s[n] = ps; al_d[n] = pd; }
}

// K5a: layer-2 aggregation, one dst per 64-thread block, 8 chains, f16 h2.
__global__ __launch_bounds__(64) void k5a(
    const __half* __restrict__ h2h, const float* __restrict__ als, const float* __restrict__ ald,
    const float* __restrict__ b2, const int* __restrict__ off, const unsigned* __restrict__ ssd,
    float* __restrict__ out2) {
    int d = blockIdx.x;
    int lane = threadIdx.x;
    int beg = off[d], end = off[d + 1];
    float adv = ald[d];
    float m[8], den[8], acc[8];
    m[0] = lrelu(als[d] + adv); den[0] = 1.f; acc[0] = __half2float(h2h[d * 64 + lane]);
    #pragma unroll
    for (int t = 1; t < 8; t++) { m[t] = -1e30f; den[t] = 0.f; acc[t] = 0.f; }
    int i = beg;
    for (; i + 7 < end; i += 8) {
        int sv[8]; float ev[8], vv[8];
        #pragma unroll
        for (int t = 0; t < 8; t++) sv[t] = (int)(ssd[i + t] & 0xffffu);
        #pragma unroll
        for (int t = 0; t < 8; t++) ev[t] = lrelu(als[sv[t]] + adv);
        #pragma unroll
        for (int t = 0; t < 8; t++) vv[t] = __half2float(h2h[sv[t] * 64 + lane]);
        #pragma unroll
        for (int t = 0; t < 8; t++) sm_upd(m[t], den[t], acc[t], ev[t], vv[t]);
    }
    for (; i < end; i++) {
        int s = (int)(ssd[i] & 0xffffu);
        sm_upd(m[0], den[0], acc[0], lrelu(als[s] + adv), __half2float(h2h[s * 64 + lane]));
    }
    #pragma unroll
    for (int t = 4; t < 8; t++) sm_merge(m[t - 4], den[t - 4], acc[t - 4], m[t], den[t], acc[t]);
    sm_merge(m[0], den[0], acc[0], m[1], den[1], acc[1]);
    sm_merge(m[2], den[2], acc[2], m[3], den[3], acc[3]);
    sm_merge(m[0], den[0], acc[0], m[2], den[2], acc[2]);
    out2[d * 64 + lane] = fmaxf(acc[0] / den[0] + b2[lane], 0.f);
}

// K5b: U = out2 @ mW1[0:64,:] + mb1, V = out2 @ mW1[64:128,:]; stored f16.
__global__ __launch_bounds__(256) void k5b(const float* __restrict__ out2,
                                           const float* __restrict__ mW1,
                                           const float* __restrict__ mb1,
                                           __half* __restrict__ Uh, __half* __restrict__ Vh) {
    __shared__ float Ws[128 * 64];
    __shared__ float o2s[4][64];
    for (int t = threadIdx.x; t < 128 * 64; t += 256) Ws[t] = mW1[t];
    __syncthreads();
    int wid = threadIdx.x >> 6, lane = threadIdx.x & 63;
    int n = blockIdx.x * 4 + wid;
    if (n >= N_NODES) return;
    o2s[wid][lane] = out2[n * 64 + lane];
    float au = mb1[lane], av = 0.f;
    #pragma unroll 8
    for (int k = 0; k < 64; k++) {
        float ov = o2s[wid][k];
        au = fmaf(ov, Ws[k * 64 + lane], au);
        av = fmaf(ov, Ws[(64 + k) * 64 + lane], av);
    }
    Uh[n * 64 + lane] = __float2half(au);
    Vh[n * 64 + lane] = __float2half(av);
}

// weight prep: bf16 hi/lo split of mW2^T, mW3^T (global; staged to LDS in k7f)
__global__ void k_wprep(const float* __restrict__ mW2, const float* __restrict__ mW3,
                        unsigned short* __restrict__ W2th, unsigned short* __restrict__ W2tl,
                        unsigned short* __restrict__ W3th, unsigned short* __restrict__ W3tl) {
    int b = blockIdx.x, t = threadIdx.x;
    float w2 = mW2[t * 64 + b];
    __hip_bfloat16 h2 = __float2bfloat16(w2);
    W2th[b * 64 + t] = __bfloat16_as_ushort(h2);
    W2tl[b * 64 + t] = __bfloat16_as_ushort(__float2bfloat16(w2 - __bfloat162float(h2)));
    float w3 = mW3[t * 64 + b];
    __hip_bfloat16 h3 = __float2bfloat16(w3);
    W3th[b * 64 + t] = __bfloat16_as_ushort(h3);
    W3tl[b * 64 + t] = __bfloat16_as_ushort(__float2bfloat16(w3 - __bfloat162float(h3)));
}

// K7f: edge MLP via MFMA. 8 waves/block, 32 edges/wave, weights+biases in LDS
// (fragment-major, conflict-free), U/V gathered as f16 (half the lines/instructions),
// bijective XCD swizzle on block index.
__global__ __launch_bounds__(512) void k7f(
    const unsigned* __restrict__ s2sd, const int* __restrict__ e2,
    const __half* __restrict__ Uh, const __half* __restrict__ Vh,
    const unsigned short* __restrict__ W2th, const unsigned short* __restrict__ W2tl,
    const unsigned short* __restrict__ W3th, const unsigned short* __restrict__ W3tl,
    const float* __restrict__ mb2, const float* __restrict__ mb3,
    const float* __restrict__ mW4, const float* __restrict__ mb4,
    float* __restrict__ out)
{
    __shared__ unsigned short Wf[4][4096];   // frag-major: [(mA*4+kb)*64+lane]*8 ushort
    __shared__ float mbS[3][64];             // mb2, mb3, mW4
    const int t = threadIdx.x;
    {
        int mA = t >> 8, kb = (t >> 6) & 3, l = t & 63;
        int src = (mA * 32 + (l & 31)) * 64 + kb * 16 + (l >> 5) * 8;
        *(uint4*)&Wf[0][t * 8] = *(const uint4*)(W2th + src);
        *(uint4*)&Wf[1][t * 8] = *(const uint4*)(W2tl + src);
        *(uint4*)&Wf[2][t * 8] = *(const uint4*)(W3th + src);
        *(uint4*)&Wf[3][t * 8] = *(const uint4*)(W3tl + src);
        if (t < 64) mbS[0][t] = mb2[t];
        else if (t < 128) mbS[1][t - 64] = mb3[t - 64];
        else if (t < 192) mbS[2][t - 128] = mW4[t - 128];
    }
    __syncthreads();

    // bijective XCD-chunked block swizzle (8 XCDs)
    const int nb = gridDim.x, q8 = nb >> 3, r8 = nb & 7;
    const int xcd = blockIdx.x & 7, bidx = blockIdx.x >> 3;
    const int wg = (xcd < r8) ? xcd * (q8 + 1) + bidx
                              : r8 * (q8 + 1) + (xcd - r8) * q8 + bidx;

    const int wid = t >> 6, lane = t & 63;
    const int tbase = wg * 256 + wid * 32;
    const int l31 = lane & 31;
    const int h = lane >> 5;
    const int ksub = h * 8;

    unsigned sd = s2sd[tbase + l31];
    int rA = (int)(sd & 0xffffu);     // src -> U
    int cA = (int)(sd >> 16);         // dst -> V
    const __half* urow = Uh + (size_t)rA * 64 + ksub;
    const __half* vrow = Vh + (size_t)cA * 64 + ksub;

    // ---- layer 2, bias init from LDS ----
    f32x16 c2[2];
    #pragma unroll
    for (int mA = 0; mA < 2; mA++)
        #pragma unroll
        for (int q = 0; q < 4; q++) {
            float4 b = *(const float4*)&mbS[0][mA * 32 + 4 * h + q * 8];
            c2[mA][q * 4 + 0] = b.x; c2[mA][q * 4 + 1] = b.y;
            c2[mA][q * 4 + 2] = b.z; c2[mA][q * 4 + 3] = b.w;
        }

    #pragma unroll
    for (int kb = 0; kb < 4; kb++) {
        __half2 uv2[4], vv2[4];
        *(uint4*)uv2 = *(const uint4*)(urow + kb * 16);
        *(uint4*)vv2 = *(const uint4*)(vrow + kb * 16);
        float z[8];
        #pragma unroll
        for (int j = 0; j < 4; j++) {
            float2 uf = __half22float2(uv2[j]);
            float2 vf = __half22float2(vv2[j]);
            z[2 * j]     = fmaxf(uf.x + vf.x, 0.f);
            z[2 * j + 1] = fmaxf(uf.y + vf.y, 0.f);
        }
        U32x4S8 bh, bl;
        #pragma unroll
        for (int q = 0; q < 4; q++) hilo2(z[2 * q], z[2 * q + 1], bh.u[q], bl.u[q]);
        #pragma unroll
        for (int mA = 0; mA < 2; mA++) {
            const int f = (mA * 4 + kb) * 64 + lane;
            short8v ah = *(const short8v*)&Wf[0][f * 8];
            short8v al = *(const short8v*)&Wf[1][f * 8];
            c2[mA] = __builtin_amdgcn_mfma_f32_32x32x16_bf16(ah, bh.s, c2[mA], 0, 0, 0);
            c2[mA] = __builtin_amdgcn_mfma_f32_32x32x16_bf16(al, bh.s, c2[mA], 0, 0, 0);
            c2[mA] = __builtin_amdgcn_mfma_f32_32x32x16_bf16(ah, bl.s, c2[mA], 0, 0, 0);
            c2[mA] = __builtin_amdgcn_mfma_f32_32x32x16_bf16(al, bl.s, c2[mA], 0, 0, 0);
        }
    }

    // ---- refragment relu(c2) -> B3 (c2 dies here) ----
    unsigned B3h[4][4], B3l[4][4];
    #pragma unroll
    for (int kbp = 0; kbp < 4; kbp++) {
        const int mAs = kbp >> 1, kbl = kbp & 1;
        float e[8];
        #pragma unroll
        for (int b = 0; b < 4; b++) {
            float u = fmaxf(c2[mAs][8 * kbl + b], 0.f);
            float v = fmaxf(c2[mAs][8 * kbl + 4 + b], 0.f);
            float su = __shfl_xor(u, 32, 64);
            float sv = __shfl_xor(v, 32, 64);
            e[b]     = h ? sv : u;
            e[4 + b] = h ? v : su;
        }
        #pragma unroll
        for (int q = 0; q < 4; q++) hilo2(e[2 * q], e[2 * q + 1], B3h[kbp][q], B3l[kbp][q]);
    }

    // ---- layer 3, bias init from LDS ----
    f32x16 c3[2];
    #pragma unroll
    for (int mA = 0; mA < 2; mA++)
        #pragma unroll
        for (int q = 0; q < 4; q++) {
            float4 b = *(const float4*)&mbS[1][mA * 32 + 4 * h + q * 8];
            c3[mA][q * 4 + 0] = b.x; c3[mA][q * 4 + 1] = b.y;
            c3[mA][q * 4 + 2] = b.z; c3[mA][q * 4 + 3] = b.w;
        }

    #pragma unroll
    for (int kbp = 0; kbp < 4; kbp++) {
        U32x4S8 bh, bl;
        #pragma unroll
        for (int q = 0; q < 4; q++) { bh.u[q] = B3h[kbp][q]; bl.u[q] = B3l[kbp][q]; }
        #pragma unroll
        for (int mA = 0; mA < 2; mA++) {
            const int f = (mA * 4 + kbp) * 64 + lane;
            short8v ah = *(const short8v*)&Wf[2][f * 8];
            short8v al = *(const short8v*)&Wf[3][f * 8];
            c3[mA] = __builtin_amdgcn_mfma_f32_32x32x16_bf16(ah, bh.s, c3[mA], 0, 0, 0);
            c3[mA] = __builtin_amdgcn_mfma_f32_32x32x16_bf16(al, bh.s, c3[mA], 0, 0, 0);
            c3[mA] = __builtin_amdgcn_mfma_f32_32x32x16_bf16(ah, bl.s, c3[mA], 0, 0, 0);
            c3[mA] = __builtin_amdgcn_mfma_f32_32x32x16_bf16(al, bl.s, c3[mA], 0, 0, 0);
        }
    }

    float p = 0.f;
    #pragma unroll
    for (int mA = 0; mA < 2; mA++)
        #pragma unroll
        for (int q = 0; q < 4; q++) {
            float4 w4 = *(const float4*)&mbS[2][mA * 32 + 4 * h + q * 8];
            p = fmaf(fmaxf(c3[mA][q * 4 + 0], 0.f), w4.x, p);
            p = fmaf(fmaxf(c3[mA][q * 4 + 1], 0.f), w4.y, p);
            p = fmaf(fmaxf(c3[mA][q * 4 + 2], 0.f), w4.z, p);
            p = fmaf(fmaxf(c3[mA][q * 4 + 3], 0.f), w4.w, p);
        }
    p += __shfl_xor(p, 32, 64);
    int eA = e2[tbase + l31];
    if (lane < 32) out[eA] = p + mb4[0];
}

extern "C" void kernel_launch(void* const* d_in, const int* in_sizes, int n_in,
                              void* d_out, int out_size, void* d_ws, size_t ws_size,
                              hipStream_t stream) {
    const float* x   = (const float*)d_in[0];
    const int*   ei  = (const int*)d_in[1];
    const float* W1  = (const float*)d_in[2];
    const float* as1 = (const float*)d_in[3];
    const float* ad1 = (const float*)d_in[4];
    const float* b1  = (const float*)d_in[5];
    const float* W2  = (const float*)d_in[6];
    const float* as2 = (const float*)d_in[7];
    const float* ad2 = (const float*)d_in[8];
    const float* b2  = (const float*)d_in[9];
    const float* mW1 = (const float*)d_in[10];
    const float* mb1 = (const float*)d_in[11];
    const float* mW2 = (const float*)d_in[12];
    const float* mb2 = (const float*)d_in[13];
    const float* mW3 = (const float*)d_in[14];
    const float* mb3 = (const float*)d_in[15];
    const float* mW4 = (const float*)d_in[16];
    const float* mb4 = (const float*)d_in[17];
    float* out = (float*)d_out;
    const int* row = ei;             // src
    const int* col = ei + N_EDGES;   // dst

    char* w = (char*)d_ws;
    __half*   Uh    = (__half*)w;                     // 6.4 MB, k5b->k7f
    __half*   Vh    = (__half*)(w + 6400000);         // 6.4 MB, k5b->k7f
    float*    out2  = (float*)(w + 12800000);         // 12.8 MB, k5a->k5b
    __half*   h2h   = (__half*)(w + 25600000);        // 6.4 MB, k4n->k5a
    unsigned* ssd   = (unsigned*)(w + 32000000);      // 6.4 MB (CSR order, dst<<16|src)
    int*      eid   = (int*)(w + 38400000);           // 6.4 MB
    unsigned* s2sd  = (unsigned*)(w + 44800000);      // 6.4 MB (2D order)
    int*      eid2  = (int*)(w + 51200000);           // 6.4 MB
    int*      deg   = (int*)(w + 57600000);           // 0.2 MB
    int*      offp  = (int*)(w + 57800000);           // 0.2 MB + 4
    int*      cursor= (int*)(w + 58000064);           // 0.2 MB
    float*    al_s2 = (float*)(w + 58200064);
    float*    al_d2 = (float*)(w + 58400064);
    int*      bsum  = (int*)(w + 58600064);           // 1 KB
    float*    qs    = (float*)(w + 58601088);
    float*    qd    = (float*)(w + 58601216);
    unsigned short* W2th = (unsigned short*)(w + 58601344);
    unsigned short* W2tl = W2th + 4096;
    unsigned short* W3th = W2th + 8192;
    unsigned short* W3tl = W2th + 12288;              // ends 58,634,112
    int*      cnt   = (int*)(w + 58634112);           // 175 KB
    int*      basep = (int*)(w + 58809112);           // 175 KB -> ends ~59.0 MB
    // overlays inside out2 region (dead before k5a writes out2):
    float*    accx  = (float*)(w + 12800000);         // 6.4 MB, k3n->k4n
    float*    denb  = (float*)(w + 19200000);         // 0.4 MB, k3n->k4n
    float*    al_s1 = (float*)(w + 19600000);         // 0.4 MB, k1n->k3n
    float*    al_d1 = (float*)(w + 20000000);         // 0.4 MB, k1n->k3n

    hipMemsetAsync(deg, 0, N_NODES * sizeof(int), stream);
    k_qprep<<<1, 64, 0, stream>>>(W1, as1, ad1, qs, qd);
    k_wprep<<<64, 64, 0, stream>>>(mW2, mW3, W2th, W2tl, W3th, W3tl);
    k1n<<<(N_NODES + 255) / 256, 256, 0, stream>>>(x, qs, qd, al_s1, al_d1);
    k_hist<<<(N_EDGES + 255) / 256, 256, 0, stream>>>(col, deg);
    k_scan1<<<(N_NODES + SCAN_B - 1) / SCAN_B, SCAN_B, 0, stream>>>(deg, offp, bsum);
    k_scan2<<<1, SCAN_B, 0, stream>>>(bsum, (N_NODES + SCAN_B - 1) / SCAN_B);
    k_scan3<<<(N_NODES + SCAN_B - 1) / SCAN_B, SCAN_B, 0, stream>>>(offp, bsum, cursor);
    k_scatter3<<<(N_EDGES + 255) / 256, 256, 0, stream>>>(row, col, cursor, ssd, eid);
    // bucket partition offsets: parallel scan over cnt[7][NBLK]
    p_hist<<<NBLK, 256, 0, stream>>>(ssd, cnt);
    {
        int n = 7 * NBLK;                             // 43750
        int nbk = (n + SCAN_B - 1) / SCAN_B;          // 171
        g_scan1<<<nbk, SCAN_B, 0, stream>>>(cnt, basep, bsum, n);
        k_scan2<<<1, SCAN_B, 0, stream>>>(bsum, nbk);
        g_add<<<nbk, SCAN_B, 0, stream>>>(basep, bsum, n);
    }
    p_scatter<<<NBLK, 256, 0, stream>>>(ssd, eid, basep, s2sd, eid2);
    k3n<<<N_NODES / 8, 256, 0, stream>>>(x, al_s1, al_d1, offp, ssd, accx, denb);
    k4n<<<N_NODES / 4, 256, 0, stream>>>(accx, denb, W1, b1, W2, as2, ad2, h2h, al_s2, al_d2);
    k5a<<<N_NODES, 64, 0, stream>>>(h2h, al_s2, al_d2, b2, offp, ssd, out2);
    k5b<<<N_NODES / 4, 256, 0, stream>>>(out2, mW1, mb1, Uh, Vh);
    k7f<<<NBLK, 512, 0, stream>>>(s2sd, eid2, Uh, Vh,
                                  W2th, W2tl, W3th, W3tl,
                                  mb2, mb3, mW4, mb4, out);
}

// Round 10
// 534.395 us; speedup vs baseline: 1.4008x; 1.0216x over previous
//
#include <hip/hip_runtime.h>
#include <hip/hip_bf16.h>
#include <hip/hip_fp16.h>
#include <math.h>

#define N_NODES 50000
#define N_EDGES 1600000
#define IN_DIM 16
#define HID 64
#define NBLK 6250          // N_EDGES / 256
#define NB1 32             // level-1 scatter buckets (dst>>11; 25 used)

typedef __attribute__((ext_vector_type(8))) short short8v;
typedef __attribute__((ext_vector_type(16))) float f32x16;

union U32x4S8 { unsigned u[4]; short8v s; };

__device__ __forceinline__ float lrelu(float v) { return v > 0.f ? v : 0.2f * v; }

__device__ __forceinline__ float wave_reduce_sum(float v) {
    #pragma unroll
    for (int off = 32; off > 0; off >>= 1) v += __shfl_down(v, off, 64);
    return v;
}

// online-softmax state update / merge
__device__ __forceinline__ void sm_upd(float& m, float& den, float& acc, float e, float v) {
    float n = fmaxf(m, e);
    float f = __expf(m - n), w = __expf(e - n);
    den = den * f + w;
    acc = acc * f + w * v;
    m = n;
}
__device__ __forceinline__ void sm_merge(float& m, float& den, float& acc,
                                         float m2, float den2, float acc2) {
    float mm = fmaxf(m, m2);
    float f1 = __expf(m - mm), f2 = __expf(m2 - mm);
    den = den * f1 + den2 * f2;
    acc = acc * f1 + acc2 * f2;
    m = mm;
}

__device__ __forceinline__ unsigned pk_bf16(float a, float b) {
    unsigned ua = (unsigned)__bfloat16_as_ushort(__float2bfloat16(a));
    unsigned ub = (unsigned)__bfloat16_as_ushort(__float2bfloat16(b));
    return ua | (ub << 16);
}
__device__ __forceinline__ void hilo2(float f0, float f1, unsigned& hw, unsigned& lw) {
    __hip_bfloat16 h0 = __float2bfloat16(f0), h1 = __float2bfloat16(f1);
    float r0 = __bfloat162float(h0), r1 = __bfloat162float(h1);
    hw = (unsigned)__bfloat16_as_ushort(h0) | ((unsigned)__bfloat16_as_ushort(h1) << 16);
    lw = pk_bf16(f0 - r0, f1 - r1);
}

// qs[i][h] = sum_c W1[i, h*64+c] * as1[h,c]  (and qd with ad1)
__global__ void k_qprep(const float* __restrict__ W1, const float* __restrict__ as1,
                        const float* __restrict__ ad1, float* __restrict__ qs, float* __restrict__ qd) {
    int t = threadIdx.x;
    if (t < 32) {
        int i = t >> 1, h = t & 1;
        float s = 0.f, d = 0.f;
        for (int c = 0; c < 64; c++) {
            float w = W1[i * 128 + h * 64 + c];
            s = fmaf(w, as1[h * 64 + c], s);
            d = fmaf(w, ad1[h * 64 + c], d);
        }
        qs[i * 2 + h] = s; qd[i * 2 + h] = d;
    }
}

__global__ void k1n(const float* __restrict__ x, const float* __restrict__ qs,
                    const float* __restrict__ qd, float* __restrict__ al_s, float* __restrict__ al_d) {
    int n = blockIdx.x * 256 + threadIdx.x;
    if (n >= N_NODES) return;
    float s0 = 0.f, s1 = 0.f, d0 = 0.f, d1 = 0.f;
    #pragma unroll
    for (int i = 0; i < IN_DIM; i++) {
        float xv = x[n * IN_DIM + i];
        s0 = fmaf(xv, qs[i * 2 + 0], s0);
        s1 = fmaf(xv, qs[i * 2 + 1], s1);
        d0 = fmaf(xv, qd[i * 2 + 0], d0);
        d1 = fmaf(xv, qd[i * 2 + 1], d1);
    }
    al_s[n * 2 + 0] = s0; al_s[n * 2 + 1] = s1;
    al_d[n * 2 + 0] = d0; al_d[n * 2 + 1] = d1;
}

#define SCAN_B 256
__global__ void k_scan1(const int* __restrict__ deg, int* __restrict__ off, int* __restrict__ bsum) {
    __shared__ int sh[SCAN_B];
    int gid = blockIdx.x * SCAN_B + threadIdx.x;
    int v = (gid < N_NODES) ? deg[gid] : 0;
    sh[threadIdx.x] = v;
    __syncthreads();
    for (int o = 1; o < SCAN_B; o <<= 1) {
        int t = (threadIdx.x >= o) ? sh[threadIdx.x - o] : 0;
        __syncthreads();
        sh[threadIdx.x] += t;
        __syncthreads();
    }
    int incl = sh[threadIdx.x];
    if (gid < N_NODES) off[gid] = incl - v;
    if (threadIdx.x == SCAN_B - 1) bsum[blockIdx.x] = incl;
}
__global__ void k_scan2(int* __restrict__ bsum, int nblocks) {
    __shared__ int sh[SCAN_B];
    int v = (threadIdx.x < nblocks) ? bsum[threadIdx.x] : 0;
    sh[threadIdx.x] = v;
    __syncthreads();
    for (int o = 1; o < SCAN_B; o <<= 1) {
        int t = (threadIdx.x >= o) ? sh[threadIdx.x - o] : 0;
        __syncthreads();
        sh[threadIdx.x] += t;
        __syncthreads();
    }
    if (threadIdx.x < nblocks) bsum[threadIdx.x] = sh[threadIdx.x] - v;
}
__global__ void k_scan3(int* __restrict__ off, const int* __restrict__ bsum, int* __restrict__ cursor) {
    int gid = blockIdx.x * SCAN_B + threadIdx.x;
    if (gid < N_NODES) {
        int o = off[gid] + bsum[blockIdx.x];
        off[gid] = o;
        cursor[gid] = o;
    }
    if (gid == 0) off[N_NODES] = N_EDGES;
}

// generalized block scan: exclusive within block, block totals to bsum
__global__ void g_scan1(const int* __restrict__ in, int* __restrict__ out,
                        int* __restrict__ bsum, int n) {
    __shared__ int sh[SCAN_B];
    int gid = blockIdx.x * SCAN_B + threadIdx.x;
    int v = (gid < n) ? in[gid] : 0;
    sh[threadIdx.x] = v;
    __syncthreads();
    for (int o = 1; o < SCAN_B; o <<= 1) {
        int t = (threadIdx.x >= o) ? sh[threadIdx.x - o] : 0;
        __syncthreads();
        sh[threadIdx.x] += t;
        __syncthreads();
    }
    int incl = sh[threadIdx.x];
    if (gid < n) out[gid] = incl - v;
    if (threadIdx.x == SCAN_B - 1) bsum[blockIdx.x] = incl;
}
__global__ void g_add(int* __restrict__ out, const int* __restrict__ bsum, int n) {
    int gid = blockIdx.x * SCAN_B + threadIdx.x;
    if (gid < n) out[gid] += bsum[blockIdx.x];
}

// ---- hierarchical CSR scatter ----
// s_hist1: global deg histogram + per-block 32-bucket (dst>>11) counts
__global__ __launch_bounds__(256) void s_hist1(const int* __restrict__ dst,
                                               int* __restrict__ deg, int* __restrict__ cnt1) {
    __shared__ int c[NB1];
    if (threadIdx.x < NB1) c[threadIdx.x] = 0;
    __syncthreads();
    int e = blockIdx.x * 256 + threadIdx.x;
    int d = dst[e];
    atomicAdd(&deg[d], 1);
    atomicAdd(&c[d >> 11], 1);
    __syncthreads();
    if (threadIdx.x < NB1) cnt1[threadIdx.x * NBLK + blockIdx.x] = c[threadIdx.x];
}

// s_scatter1: block-aggregated scatter into bucket-major u64 (line-dense writes)
__global__ __launch_bounds__(256) void s_scatter1(const int* __restrict__ src,
                                                  const int* __restrict__ dst,
                                                  const int* __restrict__ basep1,
                                                  unsigned long long* __restrict__ tmp) {
    __shared__ int c[NB1], base[NB1];
    if (threadIdx.x < NB1) c[threadIdx.x] = 0;
    __syncthreads();
    int e = blockIdx.x * 256 + threadIdx.x;
    int d = dst[e], s = src[e];
    int k = d >> 11;
    int rank = atomicAdd(&c[k], 1);
    __syncthreads();
    if (threadIdx.x < NB1) base[threadIdx.x] = basep1[threadIdx.x * NBLK + blockIdx.x];
    __syncthreads();
    unsigned long long v = ((unsigned long long)e << 32) |
                           (((unsigned)d << 16) | (unsigned)s);
    tmp[base[k] + rank] = v;
}

// s_scatter2: bucket-major sweep -> exact CSR slot via cursor atomics.
// Grid-stride with modest grid keeps the active write window L2-resident.
__global__ __launch_bounds__(256) void s_scatter2(const unsigned long long* __restrict__ tmp,
                                                  int* __restrict__ cursor,
                                                  unsigned* __restrict__ ssd,
                                                  int* __restrict__ eid) {
    for (int i = blockIdx.x * 256 + threadIdx.x; i < N_EDGES; i += gridDim.x * 256) {
        unsigned long long v = tmp[i];
        unsigned lo = (unsigned)v;
        int d = (int)(lo >> 16);
        int pos = atomicAdd(&cursor[d], 1);
        ssd[pos] = lo;
        eid[pos] = (int)(v >> 32);
    }
}

// ---- stable 7-bucket partition by src>>13 (keeps dst order within bucket) ----
__global__ __launch_bounds__(256) void p_hist(const unsigned* __restrict__ ssd, int* __restrict__ cnt) {
    __shared__ int c[7];
    if (threadIdx.x < 7) c[threadIdx.x] = 0;
    __syncthreads();
    int i = blockIdx.x * 256 + threadIdx.x;
    atomicAdd(&c[(ssd[i] & 0xffff) >> 13], 1);
    __syncthreads();
    if (threadIdx.x < 7) cnt[threadIdx.x * NBLK + blockIdx.x] = c[threadIdx.x];
}

__global__ __launch_bounds__(256) void p_scatter(
    const unsigned* __restrict__ ssd, const int* __restrict__ eid,
    const int* __restrict__ basep, unsigned* __restrict__ s2sd, int* __restrict__ e2) {
    __shared__ int wcnt[4][7];
    int wid = threadIdx.x >> 6, lane = threadIdx.x & 63;
    int i = blockIdx.x * 256 + threadIdx.x;
    unsigned v = ssd[i];
    int e = eid[i];
    int k = (v & 0xffff) >> 13;
    int rank = 0;
    #pragma unroll
    for (int kk = 0; kk < 7; kk++) {
        unsigned long long m = __ballot(k == kk);
        if (k == kk) rank = __popcll(m & ((1ull << lane) - 1ull));
        if (lane == kk) wcnt[wid][kk] = __popcll(m);
    }
    __syncthreads();
    int prev = 0;
    #pragma unroll
    for (int w = 0; w < 4; w++) if (w < wid) prev += wcnt[w][k];
    int pos = basep[k * NBLK + blockIdx.x] + prev + rank;
    s2sd[pos] = v; e2[pos] = e;
}

// K3n: layer-1 aggregation in x-space, 8 independent online-softmax chains.
__global__ void k3n(const float* __restrict__ x, const float* __restrict__ als,
                    const float* __restrict__ ald, const int* __restrict__ off,
                    const unsigned* __restrict__ ssd, float* __restrict__ accx,
                    float* __restrict__ denb) {
    int wid = threadIdx.x >> 6, lane = threadIdx.x & 63;
    int half = lane >> 5, sub = lane & 31, head = sub >> 4, ch = sub & 15;
    int d = blockIdx.x * 8 + wid * 2 + half;
    if (d >= N_NODES) return;
    int beg = off[d], end = off[d + 1];
    float adv = ald[d * 2 + head];
    float m[8], den[8], acc[8];
    m[0] = lrelu(als[d * 2 + head] + adv); den[0] = 1.f; acc[0] = x[d * IN_DIM + ch];
    #pragma unroll
    for (int t = 1; t < 8; t++) { m[t] = -1e30f; den[t] = 0.f; acc[t] = 0.f; }
    int i = beg;
    for (; i + 7 < end; i += 8) {
        int sv[8]; float ev[8], xv[8];
        #pragma unroll
        for (int t = 0; t < 8; t++) sv[t] = (int)(ssd[i + t] & 0xffffu);
        #pragma unroll
        for (int t = 0; t < 8; t++) ev[t] = lrelu(als[sv[t] * 2 + head] + adv);
        #pragma unroll
        for (int t = 0; t < 8; t++) xv[t] = x[sv[t] * IN_DIM + ch];
        #pragma unroll
        for (int t = 0; t < 8; t++) sm_upd(m[t], den[t], acc[t], ev[t], xv[t]);
    }
    for (; i < end; i++) {
        int s = (int)(ssd[i] & 0xffffu);
        sm_upd(m[0], den[0], acc[0], lrelu(als[s * 2 + head] + adv), x[s * IN_DIM + ch]);
    }
    #pragma unroll
    for (int t = 4; t < 8; t++) sm_merge(m[t - 4], den[t - 4], acc[t - 4], m[t], den[t], acc[t]);
    sm_merge(m[0], den[0], acc[0], m[1], den[1], acc[1]);
    sm_merge(m[2], den[2], acc[2], m[3], den[3], acc[3]);
    sm_merge(m[0], den[0], acc[0], m[2], den[2], acc[2]);
    accx[d * 32 + sub] = acc[0];
    if ((sub & 15) == 0) denb[d * 2 + head] = den[0];
}

// K4n: fused out1-expand then @ W2 -> h2 (f16), al_s2/al_d2.
__global__ __launch_bounds__(256) void k4n(
    const float* __restrict__ accx, const float* __restrict__ denb,
    const float* __restrict__ W1, const float* __restrict__ b1,
    const float* __restrict__ W2, const float* __restrict__ as2, const float* __restrict__ ad2,
    __half* __restrict__ h2h, float* __restrict__ al_s, float* __restrict__ al_d) {
    __shared__ float W1s[16 * 128];
    __shared__ float W2s[128 * 64];
    __shared__ float st[4][160];
    for (int t = threadIdx.x; t < 16 * 128; t += 256) W1s[t] = W1[t];
    for (int t = threadIdx.x; t < 128 * 64; t += 256) W2s[t] = W2[t];
    __syncthreads();
    int wid = threadIdx.x >> 6, lane = threadIdx.x & 63;
    int n = blockIdx.x * 4 + wid;
    if (n >= N_NODES) return;
    if (lane < 32) st[wid][lane] = accx[n * 32 + lane];
    float den0 = denb[n * 2], den1 = denb[n * 2 + 1];
    float ta = 0.f, tb = 0.f;
    #pragma unroll
    for (int i = 0; i < 16; i++) {
        ta = fmaf(st[wid][i],      W1s[i * 128 + lane],      ta);
        tb = fmaf(st[wid][16 + i], W1s[i * 128 + 64 + lane], tb);
    }
    ta = fmaxf(ta / den0 + b1[lane], 0.f);
    tb = fmaxf(tb / den1 + b1[64 + lane], 0.f);
    st[wid][32 + lane] = ta;
    st[wid][96 + lane] = tb;
    float acc = 0.f;
    #pragma unroll 8
    for (int k = 0; k < 128; k++) acc = fmaf(st[wid][32 + k], W2s[k * 64 + lane], acc);
    h2h[n * 64 + lane] = __float2half(acc);
    float ps = wave_reduce_sum(acc * as2[lane]);
    float pd = wave_reduce_sum(acc * ad2[lane]);
    if (lane == 0) { al_s[n] = ps; al_d[n] = pd; }
}

// K5a: layer-2 aggregation, one dst per 64-thread block, 8 chains, f16 h2.
__global__ __launch_bounds__(64) void k5a(
    const __half* __restrict__ h2h, const float* __restrict__ als, const float* __restrict__ ald,
    const float* __restrict__ b2, const int* __restrict__ off, const unsigned* __restrict__ ssd,
    float* __restrict__ out2) {
    int d = blockIdx.x;
    int lane = threadIdx.x;
    int beg = off[d], end = off[d + 1];
    float adv = ald[d];
    float m[8], den[8], acc[8];
    m[0] = lrelu(als[d] + adv); den[0] = 1.f; acc[0] = __half2float(h2h[d * 64 + lane]);
    #pragma unroll
    for (int t = 1; t < 8; t++) { m[t] = -1e30f; den[t] = 0.f; acc[t] = 0.f; }
    int i = beg;
    for (; i + 7 < end; i += 8) {
        int sv[8]; float ev[8], vv[8];
        #pragma unroll
        for (int t = 0; t < 8; t++) sv[t] = (int)(ssd[i + t] & 0xffffu);
        #pragma unroll
        for (int t = 0; t < 8; t++) ev[t] = lrelu(als[sv[t]] + adv);
        #pragma unroll
        for (int t = 0; t < 8; t++) vv[t] = __half2float(h2h[sv[t] * 64 + lane]);
        #pragma unroll
        for (int t = 0; t < 8; t++) sm_upd(m[t], den[t], acc[t], ev[t], vv[t]);
    }
    for (; i < end; i++) {
        int s = (int)(ssd[i] & 0xffffu);
        sm_upd(m[0], den[0], acc[0], lrelu(als[s] + adv), __half2float(h2h[s * 64 + lane]));
    }
    #pragma unroll
    for (int t = 4; t < 8; t++) sm_merge(m[t - 4], den[t - 4], acc[t - 4], m[t], den[t], acc[t]);
    sm_merge(m[0], den[0], acc[0], m[1], den[1], acc[1]);
    sm_merge(m[2], den[2], acc[2], m[3], den[3], acc[3]);
    sm_merge(m[0], den[0], acc[0], m[2], den[2], acc[2]);
    out2[d * 64 + lane] = fmaxf(acc[0] / den[0] + b2[lane], 0.f);
}

// K5b: U = out2 @ mW1[0:64,:] + mb1, V = out2 @ mW1[64:128,:]; stored f16.
__global__ __launch_bounds__(256) void k5b(const float* __restrict__ out2,
                                           const float* __restrict__ mW1,
                                           const float* __restrict__ mb1,
                                           __half* __restrict__ Uh, __half* __restrict__ Vh) {
    __shared__ float Ws[128 * 64];
    __shared__ float o2s[4][64];
    for (int t = threadIdx.x; t < 128 * 64; t += 256) Ws[t] = mW1[t];
    __syncthreads();
    int wid = threadIdx.x >> 6, lane = threadIdx.x & 63;
    int n = blockIdx.x * 4 + wid;
    if (n >= N_NODES) return;
    o2s[wid][lane] = out2[n * 64 + lane];
    float au = mb1[lane], av = 0.f;
    #pragma unroll 8
    for (int k = 0; k < 64; k++) {
        float ov = o2s[wid][k];
        au = fmaf(ov, Ws[k * 64 + lane], au);
        av = fmaf(ov, Ws[(64 + k) * 64 + lane], av);
    }
    Uh[n * 64 + lane] = __float2half(au);
    Vh[n * 64 + lane] = __float2half(av);
}

// weight prep: bf16 hi/lo split of mW2^T, mW3^T (global; staged to LDS in k7f)
__global__ void k_wprep(const float* __restrict__ mW2, const float* __restrict__ mW3,
                        unsigned short* __restrict__ W2th, unsigned short* __restrict__ W2tl,
                        unsigned short* __restrict__ W3th, unsigned short* __restrict__ W3tl) {
    int b = blockIdx.x, t = threadIdx.x;
    float w2 = mW2[t * 64 + b];
    __hip_bfloat16 h2 = __float2bfloat16(w2);
    W2th[b * 64 + t] = __bfloat16_as_ushort(h2);
    W2tl[b * 64 + t] = __bfloat16_as_ushort(__float2bfloat16(w2 - __bfloat162float(h2)));
    float w3 = mW3[t * 64 + b];
    __hip_bfloat16 h3 = __float2bfloat16(w3);
    W3th[b * 64 + t] = __bfloat16_as_ushort(h3);
    W3tl[b * 64 + t] = __bfloat16_as_ushort(__float2bfloat16(w3 - __bfloat162float(h3)));
}

// K7f: edge MLP via MFMA. 8 waves/block, 32 edges/wave, weights+biases in LDS,
// U/V gathered as f16, bijective XCD swizzle on block index.
__global__ __launch_bounds__(512) void k7f(
    const unsigned* __restrict__ s2sd, const int* __restrict__ e2,
    const __half* __restrict__ Uh, const __half* __restrict__ Vh,
    const unsigned short* __restrict__ W2th, const unsigned short* __restrict__ W2tl,
    const unsigned short* __restrict__ W3th, const unsigned short* __restrict__ W3tl,
    const float* __restrict__ mb2, const float* __restrict__ mb3,
    const float* __restrict__ mW4, const float* __restrict__ mb4,
    float* __restrict__ out)
{
    __shared__ unsigned short Wf[4][4096];   // frag-major: [(mA*4+kb)*64+lane]*8 ushort
    __shared__ float mbS[3][64];             // mb2, mb3, mW4
    const int t = threadIdx.x;
    {
        int mA = t >> 8, kb = (t >> 6) & 3, l = t & 63;
        int src = (mA * 32 + (l & 31)) * 64 + kb * 16 + (l >> 5) * 8;
        *(uint4*)&Wf[0][t * 8] = *(const uint4*)(W2th + src);
        *(uint4*)&Wf[1][t * 8] = *(const uint4*)(W2tl + src);
        *(uint4*)&Wf[2][t * 8] = *(const uint4*)(W3th + src);
        *(uint4*)&Wf[3][t * 8] = *(const uint4*)(W3tl + src);
        if (t < 64) mbS[0][t] = mb2[t];
        else if (t < 128) mbS[1][t - 64] = mb3[t - 64];
        else if (t < 192) mbS[2][t - 128] = mW4[t - 128];
    }
    __syncthreads();

    // bijective XCD-chunked block swizzle (8 XCDs)
    const int nb = gridDim.x, q8 = nb >> 3, r8 = nb & 7;
    const int xcd = blockIdx.x & 7, bidx = blockIdx.x >> 3;
    const int wg = (xcd < r8) ? xcd * (q8 + 1) + bidx
                              : r8 * (q8 + 1) + (xcd - r8) * q8 + bidx;

    const int wid = t >> 6, lane = t & 63;
    const int tbase = wg * 256 + wid * 32;
    const int l31 = lane & 31;
    const int h = lane >> 5;
    const int ksub = h * 8;

    unsigned sd = s2sd[tbase + l31];
    int rA = (int)(sd & 0xffffu);     // src -> U
    int cA = (int)(sd >> 16);         // dst -> V
    const __half* urow = Uh + (size_t)rA * 64 + ksub;
    const __half* vrow = Vh + (size_t)cA * 64 + ksub;

    // ---- layer 2, bias init from LDS ----
    f32x16 c2[2];
    #pragma unroll
    for (int mA = 0; mA < 2; mA++)
        #pragma unroll
        for (int q = 0; q < 4; q++) {
            float4 b = *(const float4*)&mbS[0][mA * 32 + 4 * h + q * 8];
            c2[mA][q * 4 + 0] = b.x; c2[mA][q * 4 + 1] = b.y;
            c2[mA][q * 4 + 2] = b.z; c2[mA][q * 4 + 3] = b.w;
        }

    #pragma unroll
    for (int kb = 0; kb < 4; kb++) {
        __half2 uv2[4], vv2[4];
        *(uint4*)uv2 = *(const uint4*)(urow + kb * 16);
        *(uint4*)vv2 = *(const uint4*)(vrow + kb * 16);
        float z[8];
        #pragma unroll
        for (int j = 0; j < 4; j++) {
            float2 uf = __half22float2(uv2[j]);
            float2 vf = __half22float2(vv2[j]);
            z[2 * j]     = fmaxf(uf.x + vf.x, 0.f);
            z[2 * j + 1] = fmaxf(uf.y + vf.y, 0.f);
        }
        U32x4S8 bh, bl;
        #pragma unroll
        for (int q = 0; q < 4; q++) hilo2(z[2 * q], z[2 * q + 1], bh.u[q], bl.u[q]);
        #pragma unroll
        for (int mA = 0; mA < 2; mA++) {
            const int f = (mA * 4 + kb) * 64 + lane;
            short8v ah = *(const short8v*)&Wf[0][f * 8];
            short8v al = *(const short8v*)&Wf[1][f * 8];
            c2[mA] = __builtin_amdgcn_mfma_f32_32x32x16_bf16(ah, bh.s, c2[mA], 0, 0, 0);
            c2[mA] = __builtin_amdgcn_mfma_f32_32x32x16_bf16(al, bh.s, c2[mA], 0, 0, 0);
            c2[mA] = __builtin_amdgcn_mfma_f32_32x32x16_bf16(ah, bl.s, c2[mA], 0, 0, 0);
            c2[mA] = __builtin_amdgcn_mfma_f32_32x32x16_bf16(al, bl.s, c2[mA], 0, 0, 0);
        }
    }

    // ---- refragment relu(c2) -> B3 (c2 dies here) ----
    unsigned B3h[4][4], B3l[4][4];
    #pragma unroll
    for (int kbp = 0; kbp < 4; kbp++) {
        const int mAs = kbp >> 1, kbl = kbp & 1;
        float e[8];
        #pragma unroll
        for (int b = 0; b < 4; b++) {
            float u = fmaxf(c2[mAs][8 * kbl + b], 0.f);
            float v = fmaxf(c2[mAs][8 * kbl + 4 + b], 0.f);
            float su = __shfl_xor(u, 32, 64);
            float sv = __shfl_xor(v, 32, 64);
            e[b]     = h ? sv : u;
            e[4 + b] = h ? v : su;
        }
        #pragma unroll
        for (int q = 0; q < 4; q++) hilo2(e[2 * q], e[2 * q + 1], B3h[kbp][q], B3l[kbp][q]);
    }

    // ---- layer 3, bias init from LDS ----
    f32x16 c3[2];
    #pragma unroll
    for (int mA = 0; mA < 2; mA++)
        #pragma unroll
        for (int q = 0; q < 4; q++) {
            float4 b = *(const float4*)&mbS[1][mA * 32 + 4 * h + q * 8];
            c3[mA][q * 4 + 0] = b.x; c3[mA][q * 4 + 1] = b.y;
            c3[mA][q * 4 + 2] = b.z; c3[mA][q * 4 + 3] = b.w;
        }

    #pragma unroll
    for (int kbp = 0; kbp < 4; kbp++) {
        U32x4S8 bh, bl;
        #pragma unroll
        for (int q = 0; q < 4; q++) { bh.u[q] = B3h[kbp][q]; bl.u[q] = B3l[kbp][q]; }
        #pragma unroll
        for (int mA = 0; mA < 2; mA++) {
            const int f = (mA * 4 + kbp) * 64 + lane;
            short8v ah = *(const short8v*)&Wf[2][f * 8];
            short8v al = *(const short8v*)&Wf[3][f * 8];
            c3[mA] = __builtin_amdgcn_mfma_f32_32x32x16_bf16(ah, bh.s, c3[mA], 0, 0, 0);
            c3[mA] = __builtin_amdgcn_mfma_f32_32x32x16_bf16(al, bh.s, c3[mA], 0, 0, 0);
            c3[mA] = __builtin_amdgcn_mfma_f32_32x32x16_bf16(ah, bl.s, c3[mA], 0, 0, 0);
            c3[mA] = __builtin_amdgcn_mfma_f32_32x32x16_bf16(al, bl.s, c3[mA], 0, 0, 0);
        }
    }

    float p = 0.f;
    #pragma unroll
    for (int mA = 0; mA < 2; mA++)
        #pragma unroll
        for (int q = 0; q < 4; q++) {
            float4 w4 = *(const float4*)&mbS[2][mA * 32 + 4 * h + q * 8];
            p = fmaf(fmaxf(c3[mA][q * 4 + 0], 0.f), w4.x, p);
            p = fmaf(fmaxf(c3[mA][q * 4 + 1], 0.f), w4.y, p);
            p = fmaf(fmaxf(c3[mA][q * 4 + 2], 0.f), w4.z, p);
            p = fmaf(fmaxf(c3[mA][q * 4 + 3], 0.f), w4.w, p);
        }
    p += __shfl_xor(p, 32, 64);
    int eA = e2[tbase + l31];
    if (lane < 32) out[eA] = p + mb4[0];
}

extern "C" void kernel_launch(void* const* d_in, const int* in_sizes, int n_in,
                              void* d_out, int out_size, void* d_ws, size_t ws_size,
                              hipStream_t stream) {
    const float* x   = (const float*)d_in[0];
    const int*   ei  = (const int*)d_in[1];
    const float* W1  = (const float*)d_in[2];
    const float* as1 = (const float*)d_in[3];
    const float* ad1 = (const float*)d_in[4];
    const float* b1  = (const float*)d_in[5];
    const float* W2  = (const float*)d_in[6];
    const float* as2 = (const float*)d_in[7];
    const float* ad2 = (const float*)d_in[8];
    const float* b2  = (const float*)d_in[9];
    const float* mW1 = (const float*)d_in[10];
    const float* mb1 = (const float*)d_in[11];
    const float* mW2 = (const float*)d_in[12];
    const float* mb2 = (const float*)d_in[13];
    const float* mW3 = (const float*)d_in[14];
    const float* mb3 = (const float*)d_in[15];
    const float* mW4 = (const float*)d_in[16];
    const float* mb4 = (const float*)d_in[17];
    float* out = (float*)d_out;
    const int* row = ei;             // src
    const int* col = ei + N_EDGES;   // dst

    char* w = (char*)d_ws;
    __half*   Uh    = (__half*)w;                     // 6.4 MB, k5b->k7f
    __half*   Vh    = (__half*)(w + 6400000);         // 6.4 MB, k5b->k7f
    float*    out2  = (float*)(w + 12800000);         // 12.8 MB, k5a->k5b
    __half*   h2h   = (__half*)(w + 25600000);        // 6.4 MB, k4n->k5a
    unsigned* ssd   = (unsigned*)(w + 32000000);      // 6.4 MB (CSR order, dst<<16|src)
    int*      eid   = (int*)(w + 38400000);           // 6.4 MB
    unsigned* s2sd  = (unsigned*)(w + 44800000);      // 6.4 MB (2D order)
    int*      eid2  = (int*)(w + 51200000);           // 6.4 MB
    int*      deg   = (int*)(w + 57600000);           // 0.2 MB
    int*      offp  = (int*)(w + 57800000);           // 0.2 MB + 4
    int*      cursor= (int*)(w + 58000064);           // 0.2 MB
    float*    al_s2 = (float*)(w + 58200064);
    float*    al_d2 = (float*)(w + 58400064);
    int*      bsum  = (int*)(w + 58600064);           // 4 KB (scan temps, reused)
    float*    qs    = (float*)(w + 58605056);
    float*    qd    = (float*)(w + 58605184);
    unsigned short* W2th = (unsigned short*)(w + 58605312);
    unsigned short* W2tl = W2th + 4096;
    unsigned short* W3th = W2th + 8192;
    unsigned short* W3tl = W2th + 12288;              // ends 58,638,080
    int*      cnt   = (int*)(w + 58638080);           // 7*NBLK*4 = 175 KB
    int*      basep = (int*)(w + 58813080);           // 175 KB
    int*      cnt1  = (int*)(w + 58988984 + 8);       // NB1*NBLK*4 = 800 KB
    int*      basep1= (int*)(w + 59789000);           // 800 KB
    int*      bsumA = (int*)(w + 60589000);           // 782*4
    // overlays:
    float*    accx  = (float*)(w + 12800000);         // 6.4 MB, k3n->k4n (inside out2)
    float*    denb  = (float*)(w + 19200000);         // 0.4 MB, k3n->k4n
    float*    al_s1 = (float*)(w + 19600000);         // 0.4 MB, k1n->k3n
    float*    al_d1 = (float*)(w + 20000000);         // 0.4 MB, k1n->k3n
    unsigned long long* tmp = (unsigned long long*)(w + 44800000);  // 12.8 MB, overlays s2sd+eid2 (dead until p_scatter)

    hipMemsetAsync(deg, 0, N_NODES * sizeof(int), stream);
    k_qprep<<<1, 64, 0, stream>>>(W1, as1, ad1, qs, qd);
    k_wprep<<<64, 64, 0, stream>>>(mW2, mW3, W2th, W2tl, W3th, W3tl);
    k1n<<<(N_NODES + 255) / 256, 256, 0, stream>>>(x, qs, qd, al_s1, al_d1);
    // histograms: global deg + per-block level-1 bucket counts
    s_hist1<<<NBLK, 256, 0, stream>>>(col, deg, cnt1);
    // CSR offsets
    k_scan1<<<(N_NODES + SCAN_B - 1) / SCAN_B, SCAN_B, 0, stream>>>(deg, offp, bsum);
    k_scan2<<<1, SCAN_B, 0, stream>>>(bsum, (N_NODES + SCAN_B - 1) / SCAN_B);
    k_scan3<<<(N_NODES + SCAN_B - 1) / SCAN_B, SCAN_B, 0, stream>>>(offp, bsum, cursor);
    // level-1 bucket bases: 3-level scan over cnt1[NB1][NBLK] (200000 entries)
    {
        int n1 = NB1 * NBLK;                          // 200000
        int nb1 = (n1 + SCAN_B - 1) / SCAN_B;         // 782
        int nb2 = (nb1 + SCAN_B - 1) / SCAN_B;        // 4
        g_scan1<<<nb1, SCAN_B, 0, stream>>>(cnt1, basep1, bsumA, n1);
        g_scan1<<<nb2, SCAN_B, 0, stream>>>(bsumA, bsumA, bsum, nb1);
        k_scan2<<<1, SCAN_B, 0, stream>>>(bsum, nb2);
        g_add<<<nb2, SCAN_B, 0, stream>>>(bsumA, bsum, nb1);
        g_add<<<nb1, SCAN_B, 0, stream>>>(basep1, bsumA, n1);
    }
    // hierarchical scatter: edges -> bucket-major tmp -> exact CSR slots
    s_scatter1<<<NBLK, 256, 0, stream>>>(row, col, basep1, tmp);
    s_scatter2<<<1024, 256, 0, stream>>>(tmp, cursor, ssd, eid);
    // 7-bucket src partition for k7f (reads CSR, writes 2D order over tmp region)
    p_hist<<<NBLK, 256, 0, stream>>>(ssd, cnt);
    {
        int n = 7 * NBLK;                             // 43750
        int nbk = (n + SCAN_B - 1) / SCAN_B;          // 171
        g_scan1<<<nbk, SCAN_B, 0, stream>>>(cnt, basep, bsum, n);
        k_scan2<<<1, SCAN_B, 0, stream>>>(bsum, nbk);
        g_add<<<nbk, SCAN_B, 0, stream>>>(basep, bsum, n);
    }
    p_scatter<<<NBLK, 256, 0, stream>>>(ssd, eid, basep, s2sd, eid2);
    k3n<<<N_NODES / 8, 256, 0, stream>>>(x, al_s1, al_d1, offp, ssd, accx, denb);
    k4n<<<N_NODES / 4, 256, 0, stream>>>(accx, denb, W1, b1, W2, as2, ad2, h2h, al_s2, al_d2);
    k5a<<<N_NODES, 64, 0, stream>>>(h2h, al_s2, al_d2, b2, offp, ssd, out2);
    k5b<<<N_NODES / 4, 256, 0, stream>>>(out2, mW1, mb1, Uh, Vh);
    k7f<<<NBLK, 512, 0, stream>>>(s2sd, eid2, Uh, Vh,
                                  W2th, W2tl, W3th, W3tl,
                                  mb2, mb3, mW4, mb4, out);
}

// Round 12
// 513.003 us; speedup vs baseline: 1.4592x; 1.0417x over previous
//
#include <hip/hip_runtime.h>
#include <hip/hip_bf16.h>
#include <hip/hip_fp16.h>
#include <math.h>

#define N_NODES 50000
#define N_EDGES 1600000
#define IN_DIM 16
#define HID 64
#define NBLK 6250          // N_EDGES / 256
#define NB1 32             // level-1 scatter buckets (dst>>11; 25 used)

typedef __attribute__((ext_vector_type(8))) _Float16 half8v;
typedef __attribute__((ext_vector_type(16))) float f32x16;

union H8 { uint4 u4; half8v v; };

__device__ __forceinline__ float lrelu(float v) { return v > 0.f ? v : 0.2f * v; }

__device__ __forceinline__ float wave_reduce_sum(float v) {
    #pragma unroll
    for (int off = 32; off > 0; off >>= 1) v += __shfl_down(v, off, 64);
    return v;
}

// online-softmax state update / merge
__device__ __forceinline__ void sm_upd(float& m, float& den, float& acc, float e, float v) {
    float n = fmaxf(m, e);
    float f = __expf(m - n), w = __expf(e - n);
    den = den * f + w;
    acc = acc * f + w * v;
    m = n;
}
__device__ __forceinline__ void sm_merge(float& m, float& den, float& acc,
                                         float m2, float den2, float acc2) {
    float mm = fmaxf(m, m2);
    float f1 = __expf(m - mm), f2 = __expf(m2 - mm);
    den = den * f1 + den2 * f2;
    acc = acc * f1 + acc2 * f2;
    m = mm;
}

// qs[i][h] = sum_c W1[i, h*64+c] * as1[h,c]  (and qd with ad1)
__global__ void k_qprep(const float* __restrict__ W1, const float* __restrict__ as1,
                        const float* __restrict__ ad1, float* __restrict__ qs, float* __restrict__ qd) {
    int t = threadIdx.x;
    if (t < 32) {
        int i = t >> 1, h = t & 1;
        float s = 0.f, d = 0.f;
        for (int c = 0; c < 64; c++) {
            float w = W1[i * 128 + h * 64 + c];
            s = fmaf(w, as1[h * 64 + c], s);
            d = fmaf(w, ad1[h * 64 + c], d);
        }
        qs[i * 2 + h] = s; qd[i * 2 + h] = d;
    }
}

__global__ void k1n(const float* __restrict__ x, const float* __restrict__ qs,
                    const float* __restrict__ qd, float* __restrict__ al_s, float* __restrict__ al_d) {
    int n = blockIdx.x * 256 + threadIdx.x;
    if (n >= N_NODES) return;
    float s0 = 0.f, s1 = 0.f, d0 = 0.f, d1 = 0.f;
    #pragma unroll
    for (int i = 0; i < IN_DIM; i++) {
        float xv = x[n * IN_DIM + i];
        s0 = fmaf(xv, qs[i * 2 + 0], s0);
        s1 = fmaf(xv, qs[i * 2 + 1], s1);
        d0 = fmaf(xv, qd[i * 2 + 0], d0);
        d1 = fmaf(xv, qd[i * 2 + 1], d1);
    }
    al_s[n * 2 + 0] = s0; al_s[n * 2 + 1] = s1;
    al_d[n * 2 + 0] = d0; al_d[n * 2 + 1] = d1;
}

#define SCAN_B 256
__global__ void k_scan1(const int* __restrict__ deg, int* __restrict__ off, int* __restrict__ bsum) {
    __shared__ int sh[SCAN_B];
    int gid = blockIdx.x * SCAN_B + threadIdx.x;
    int v = (gid < N_NODES) ? deg[gid] : 0;
    sh[threadIdx.x] = v;
    __syncthreads();
    for (int o = 1; o < SCAN_B; o <<= 1) {
        int t = (threadIdx.x >= o) ? sh[threadIdx.x - o] : 0;
        __syncthreads();
        sh[threadIdx.x] += t;
        __syncthreads();
    }
    int incl = sh[threadIdx.x];
    if (gid < N_NODES) off[gid] = incl - v;
    if (threadIdx.x == SCAN_B - 1) bsum[blockIdx.x] = incl;
}
__global__ void k_scan2(int* __restrict__ bsum, int nblocks) {
    __shared__ int sh[SCAN_B];
    int v = (threadIdx.x < nblocks) ? bsum[threadIdx.x] : 0;
    sh[threadIdx.x] = v;
    __syncthreads();
    for (int o = 1; o < SCAN_B; o <<= 1) {
        int t = (threadIdx.x >= o) ? sh[threadIdx.x - o] : 0;
        __syncthreads();
        sh[threadIdx.x] += t;
        __syncthreads();
    }
    if (threadIdx.x < nblocks) bsum[threadIdx.x] = sh[threadIdx.x] - v;
}
__global__ void k_scan3(int* __restrict__ off, const int* __restrict__ bsum, int* __restrict__ cursor) {
    int gid = blockIdx.x * SCAN_B + threadIdx.x;
    if (gid < N_NODES) {
        int o = off[gid] + bsum[blockIdx.x];
        off[gid] = o;
        cursor[gid] = o;
    }
    if (gid == 0) off[N_NODES] = N_EDGES;
}

// generalized block scan: exclusive within block, block totals to bsum
__global__ void g_scan1(const int* __restrict__ in, int* __restrict__ out,
                        int* __restrict__ bsum, int n) {
    __shared__ int sh[SCAN_B];
    int gid = blockIdx.x * SCAN_B + threadIdx.x;
    int v = (gid < n) ? in[gid] : 0;
    sh[threadIdx.x] = v;
    __syncthreads();
    for (int o = 1; o < SCAN_B; o <<= 1) {
        int t = (threadIdx.x >= o) ? sh[threadIdx.x - o] : 0;
        __syncthreads();
        sh[threadIdx.x] += t;
        __syncthreads();
    }
    int incl = sh[threadIdx.x];
    if (gid < n) out[gid] = incl - v;
    if (threadIdx.x == SCAN_B - 1) bsum[blockIdx.x] = incl;
}
__global__ void g_add(int* __restrict__ out, const int* __restrict__ bsum, int n) {
    int gid = blockIdx.x * SCAN_B + threadIdx.x;
    if (gid < n) out[gid] += bsum[blockIdx.x];
}

// ---- hierarchical CSR scatter ----
__global__ __launch_bounds__(256) void s_hist1(const int* __restrict__ dst,
                                               int* __restrict__ deg, int* __restrict__ cnt1) {
    __shared__ int c[NB1];
    if (threadIdx.x < NB1) c[threadIdx.x] = 0;
    __syncthreads();
    int e = blockIdx.x * 256 + threadIdx.x;
    int d = dst[e];
    atomicAdd(&deg[d], 1);
    atomicAdd(&c[d >> 11], 1);
    __syncthreads();
    if (threadIdx.x < NB1) cnt1[threadIdx.x * NBLK + blockIdx.x] = c[threadIdx.x];
}

__global__ __launch_bounds__(256) void s_scatter1(const int* __restrict__ src,
                                                  const int* __restrict__ dst,
                                                  const int* __restrict__ basep1,
                                                  unsigned long long* __restrict__ tmp) {
    __shared__ int c[NB1], base[NB1];
    if (threadIdx.x < NB1) c[threadIdx.x] = 0;
    __syncthreads();
    int e = blockIdx.x * 256 + threadIdx.x;
    int d = dst[e], s = src[e];
    int k = d >> 11;
    int rank = atomicAdd(&c[k], 1);
    __syncthreads();
    if (threadIdx.x < NB1) base[threadIdx.x] = basep1[threadIdx.x * NBLK + blockIdx.x];
    __syncthreads();
    unsigned long long v = ((unsigned long long)e << 32) |
                           (((unsigned)d << 16) | (unsigned)s);
    tmp[base[k] + rank] = v;
}

__global__ __launch_bounds__(256) void s_scatter2(const unsigned long long* __restrict__ tmp,
                                                  int* __restrict__ cursor,
                                                  unsigned* __restrict__ ssd,
                                                  int* __restrict__ eid) {
    for (int i = blockIdx.x * 256 + threadIdx.x; i < N_EDGES; i += gridDim.x * 256) {
        unsigned long long v = tmp[i];
        unsigned lo = (unsigned)v;
        int d = (int)(lo >> 16);
        int pos = atomicAdd(&cursor[d], 1);
        ssd[pos] = lo;
        eid[pos] = (int)(v >> 32);
    }
}

// ---- stable 7-bucket partition by src>>13 (keeps dst order within bucket) ----
__global__ __launch_bounds__(256) void p_hist(const unsigned* __restrict__ ssd, int* __restrict__ cnt) {
    __shared__ int c[7];
    if (threadIdx.x < 7) c[threadIdx.x] = 0;
    __syncthreads();
    int i = blockIdx.x * 256 + threadIdx.x;
    atomicAdd(&c[(ssd[i] & 0xffff) >> 13], 1);
    __syncthreads();
    if (threadIdx.x < 7) cnt[threadIdx.x * NBLK + blockIdx.x] = c[threadIdx.x];
}

__global__ __launch_bounds__(256) void p_scatter(
    const unsigned* __restrict__ ssd, const int* __restrict__ eid,
    const int* __restrict__ basep, unsigned* __restrict__ s2sd, int* __restrict__ e2) {
    __shared__ int wcnt[4][7];
    int wid = threadIdx.x >> 6, lane = threadIdx.x & 63;
    int i = blockIdx.x * 256 + threadIdx.x;
    unsigned v = ssd[i];
    int e = eid[i];
    int k = (v & 0xffff) >> 13;
    int rank = 0;
    #pragma unroll
    for (int kk = 0; kk < 7; kk++) {
        unsigned long long m = __ballot(k == kk);
        if (k == kk) rank = __popcll(m & ((1ull << lane) - 1ull));
        if (lane == kk) wcnt[wid][kk] = __popcll(m);
    }
    __syncthreads();
    int prev = 0;
    #pragma unroll
    for (int w = 0; w < 4; w++) if (w < wid) prev += wcnt[w][k];
    int pos = basep[k * NBLK + blockIdx.x] + prev + rank;
    s2sd[pos] = v; e2[pos] = e;
}

// K3n: layer-1 aggregation in x-space, 8 independent online-softmax chains.
__global__ void k3n(const float* __restrict__ x, const float* __restrict__ als,
                    const float* __restrict__ ald, const int* __restrict__ off,
                    const unsigned* __restrict__ ssd, float* __restrict__ accx,
                    float* __restrict__ denb) {
    int wid = threadIdx.x >> 6, lane = threadIdx.x & 63;
    int half = lane >> 5, sub = lane & 31, head = sub >> 4, ch = sub & 15;
    int d = blockIdx.x * 8 + wid * 2 + half;
    if (d >= N_NODES) return;
    int beg = off[d], end = off[d + 1];
    float adv = ald[d * 2 + head];
    float m[8], den[8], acc[8];
    m[0] = lrelu(als[d * 2 + head] + adv); den[0] = 1.f; acc[0] = x[d * IN_DIM + ch];
    #pragma unroll
    for (int t = 1; t < 8; t++) { m[t] = -1e30f; den[t] = 0.f; acc[t] = 0.f; }
    int i = beg;
    for (; i + 7 < end; i += 8) {
        int sv[8]; float ev[8], xv[8];
        #pragma unroll
        for (int t = 0; t < 8; t++) sv[t] = (int)(ssd[i + t] & 0xffffu);
        #pragma unroll
        for (int t = 0; t < 8; t++) ev[t] = lrelu(als[sv[t] * 2 + head] + adv);
        #pragma unroll
        for (int t = 0; t < 8; t++) xv[t] = x[sv[t] * IN_DIM + ch];
        #pragma unroll
        for (int t = 0; t < 8; t++) sm_upd(m[t], den[t], acc[t], ev[t], xv[t]);
    }
    for (; i < end; i++) {
        int s = (int)(ssd[i] & 0xffffu);
        sm_upd(m[0], den[0], acc[0], lrelu(als[s * 2 + head] + adv), x[s * IN_DIM + ch]);
    }
    #pragma unroll
    for (int t = 4; t < 8; t++) sm_merge(m[t - 4], den[t - 4], acc[t - 4], m[t], den[t], acc[t]);
    sm_merge(m[0], den[0], acc[0], m[1], den[1], acc[1]);
    sm_merge(m[2], den[2], acc[2], m[3], den[3], acc[3]);
    sm_merge(m[0], den[0], acc[0], m[2], den[2], acc[2]);
    accx[d * 32 + sub] = acc[0];
    if ((sub & 15) == 0) denb[d * 2 + head] = den[0];
}

// K4n: fused out1-expand then @ W2 -> h2 (f16), al_s2/al_d2.
__global__ __launch_bounds__(256) void k4n(
    const float* __restrict__ accx, const float* __restrict__ denb,
    const float* __restrict__ W1, const float* __restrict__ b1,
    const float* __restrict__ W2, const float* __restrict__ as2, const float* __restrict__ ad2,
    __half* __restrict__ h2h, float* __restrict__ al_s, float* __restrict__ al_d) {
    __shared__ float W1s[16 * 128];
    __shared__ float W2s[128 * 64];
    __shared__ float st[4][160];
    for (int t = threadIdx.x; t < 16 * 128; t += 256) W1s[t] = W1[t];
    for (int t = threadIdx.x; t < 128 * 64; t += 256) W2s[t] = W2[t];
    __syncthreads();
    int wid = threadIdx.x >> 6, lane = threadIdx.x & 63;
    int n = blockIdx.x * 4 + wid;
    if (n >= N_NODES) return;
    if (lane < 32) st[wid][lane] = accx[n * 32 + lane];
    float den0 = denb[n * 2], den1 = denb[n * 2 + 1];
    float ta = 0.f, tb = 0.f;
    #pragma unroll
    for (int i = 0; i < 16; i++) {
        ta = fmaf(st[wid][i],      W1s[i * 128 + lane],      ta);
        tb = fmaf(st[wid][16 + i], W1s[i * 128 + 64 + lane], tb);
    }
    ta = fmaxf(ta / den0 + b1[lane], 0.f);
    tb = fmaxf(tb / den1 + b1[64 + lane], 0.f);
    st[wid][32 + lane] = ta;
    st[wid][96 + lane] = tb;
    float acc = 0.f;
    #pragma unroll 8
    for (int k = 0; k < 128; k++) acc = fmaf(st[wid][32 + k], W2s[k * 64 + lane], acc);
    h2h[n * 64 + lane] = __float2half(acc);
    float ps = wave_reduce_sum(acc * as2[lane]);
    float pd = wave_reduce_sum(acc * ad2[lane]);
    if (lane == 0) { al_s[n] = ps; al_d[n] = pd; }
}

// K5a: layer-2 aggregation, one dst per 64-thread block, 8 chains, f16 h2.
__global__ __launch_bounds__(64) void k5a(
    const __half* __restrict__ h2h, const float* __restrict__ als, const float* __restrict__ ald,
    const float* __restrict__ b2, const int* __restrict__ off, const unsigned* __restrict__ ssd,
    float* __restrict__ out2) {
    int d = blockIdx.x;
    int lane = threadIdx.x;
    int beg = off[d], end = off[d + 1];
    float adv = ald[d];
    float m[8], den[8], acc[8];
    m[0] = lrelu(als[d] + adv); den[0] = 1.f; acc[0] = __half2float(h2h[d * 64 + lane]);
    #pragma unroll
    for (int t = 1; t < 8; t++) { m[t] = -1e30f; den[t] = 0.f; acc[t] = 0.f; }
    int i = beg;
    for (; i + 7 < end; i += 8) {
        int sv[8]; float ev[8], vv[8];
        #pragma unroll
        for (int t = 0; t < 8; t++) sv[t] = (int)(ssd[i + t] & 0xffffu);
        #pragma unroll
        for (int t = 0; t < 8; t++) ev[t] = lrelu(als[sv[t]] + adv);
        #pragma unroll
        for (int t = 0; t < 8; t++) vv[t] = __half2float(h2h[sv[t] * 64 + lane]);
        #pragma unroll
        for (int t = 0; t < 8; t++) sm_upd(m[t], den[t], acc[t], ev[t], vv[t]);
    }
    for (; i < end; i++) {
        int s = (int)(ssd[i] & 0xffffu);
        sm_upd(m[0], den[0], acc[0], lrelu(als[s] + adv), __half2float(h2h[s * 64 + lane]));
    }
    #pragma unroll
    for (int t = 4; t < 8; t++) sm_merge(m[t - 4], den[t - 4], acc[t - 4], m[t], den[t], acc[t]);
    sm_merge(m[0], den[0], acc[0], m[1], den[1], acc[1]);
    sm_merge(m[2], den[2], acc[2], m[3], den[3], acc[3]);
    sm_merge(m[0], den[0], acc[0], m[2], den[2], acc[2]);
    out2[d * 64 + lane] = fmaxf(acc[0] / den[0] + b2[lane], 0.f);
}

// K5b: U = out2 @ mW1[0:64,:] + mb1, V = out2 @ mW1[64:128,:]; stored f16.
__global__ __launch_bounds__(256) void k5b(const float* __restrict__ out2,
                                           const float* __restrict__ mW1,
                                           const float* __restrict__ mb1,
                                           __half* __restrict__ Uh, __half* __restrict__ Vh) {
    __shared__ float Ws[128 * 64];
    __shared__ float o2s[4][64];
    for (int t = threadIdx.x; t < 128 * 64; t += 256) Ws[t] = mW1[t];
    __syncthreads();
    int wid = threadIdx.x >> 6, lane = threadIdx.x & 63;
    int n = blockIdx.x * 4 + wid;
    if (n >= N_NODES) return;
    o2s[wid][lane] = out2[n * 64 + lane];
    float au = mb1[lane], av = 0.f;
    #pragma unroll 8
    for (int k = 0; k < 64; k++) {
        float ov = o2s[wid][k];
        au = fmaf(ov, Ws[k * 64 + lane], au);
        av = fmaf(ov, Ws[(64 + k) * 64 + lane], av);
    }
    Uh[n * 64 + lane] = __float2half(au);
    Vh[n * 64 + lane] = __float2half(av);
}

// weight prep: f16 hi/lo split of mW2^T, mW3^T (2-product scheme; w = wh + wl exact to ~2^-22)
__global__ void k_wprep(const float* __restrict__ mW2, const float* __restrict__ mW3,
                        __half* __restrict__ W2th, __half* __restrict__ W2tl,
                        __half* __restrict__ W3th, __half* __restrict__ W3tl) {
    int b = blockIdx.x, t = threadIdx.x;
    float w2 = mW2[t * 64 + b];
    __half h2 = __float2half(w2);
    W2th[b * 64 + t] = h2;
    W2tl[b * 64 + t] = __float2half(w2 - __half2float(h2));
    float w3 = mW3[t * 64 + b];
    __half h3 = __float2half(w3);
    W3th[b * 64 + t] = h3;
    W3tl[b * 64 + t] = __float2half(w3 - __half2float(h3));
}

// K7g: edge MLP via f16 MFMA (2-product weight split, packed-f16 z build).
// 8 waves/block, 32 edges/wave, weights+biases in LDS, XCD swizzle.
__global__ __launch_bounds__(512) void k7g(
    const unsigned* __restrict__ s2sd, const int* __restrict__ e2,
    const __half* __restrict__ Uh, const __half* __restrict__ Vh,
    const __half* __restrict__ W2th, const __half* __restrict__ W2tl,
    const __half* __restrict__ W3th, const __half* __restrict__ W3tl,
    const float* __restrict__ mb2, const float* __restrict__ mb3,
    const float* __restrict__ mW4, const float* __restrict__ mb4,
    float* __restrict__ out)
{
    __shared__ unsigned short Wf[4][4096];   // frag-major f16: [(mA*4+kb)*64+lane]*8
    __shared__ float mbS[3][64];             // mb2, mb3, mW4
    const int t = threadIdx.x;
    {
        int mA = t >> 8, kb = (t >> 6) & 3, l = t & 63;
        int src = (mA * 32 + (l & 31)) * 64 + kb * 16 + (l >> 5) * 8;
        *(uint4*)&Wf[0][t * 8] = *(const uint4*)(W2th + src);
        *(uint4*)&Wf[1][t * 8] = *(const uint4*)(W2tl + src);
        *(uint4*)&Wf[2][t * 8] = *(const uint4*)(W3th + src);
        *(uint4*)&Wf[3][t * 8] = *(const uint4*)(W3tl + src);
        if (t < 64) mbS[0][t] = mb2[t];
        else if (t < 128) mbS[1][t - 64] = mb3[t - 64];
        else if (t < 192) mbS[2][t - 128] = mW4[t - 128];
    }
    __syncthreads();

    // bijective XCD-chunked block swizzle (8 XCDs)
    const int nb = gridDim.x, q8 = nb >> 3, r8 = nb & 7;
    const int xcd = blockIdx.x & 7, bidx = blockIdx.x >> 3;
    const int wg = (xcd < r8) ? xcd * (q8 + 1) + bidx
                              : r8 * (q8 + 1) + (xcd - r8) * q8 + bidx;

    const int wid = t >> 6, lane = t & 63;
    const int tbase = wg * 256 + wid * 32;
    const int l31 = lane & 31;
    const int h = lane >> 5;
    const int ksub = h * 8;

    unsigned sd = s2sd[tbase + l31];
    int rA = (int)(sd & 0xffffu);     // src -> U
    int cA = (int)(sd >> 16);         // dst -> V
    const __half* urow = Uh + (size_t)rA * 64 + ksub;
    const __half* vrow = Vh + (size_t)cA * 64 + ksub;

    // ---- layer 2, bias init from LDS ----
    f32x16 c2[2];
    #pragma unroll
    for (int mA = 0; mA < 2; mA++)
        #pragma unroll
        for (int q = 0; q < 4; q++) {
            float4 b = *(const float4*)&mbS[0][mA * 32 + 4 * h + q * 8];
            c2[mA][q * 4 + 0] = b.x; c2[mA][q * 4 + 1] = b.y;
            c2[mA][q * 4 + 2] = b.z; c2[mA][q * 4 + 3] = b.w;
        }

    #pragma unroll
    for (int kb = 0; kb < 4; kb++) {
        H8 uvu, vvu, zz;
        uvu.u4 = *(const uint4*)(urow + kb * 16);
        vvu.u4 = *(const uint4*)(vrow + kb * 16);
        {
            half8v s = uvu.v + vvu.v;   // v_pk_add_f16
            #pragma unroll
            for (int j = 0; j < 8; j++) {
                _Float16 a = s[j];
                zz.v[j] = a > (_Float16)0 ? a : (_Float16)0;   // v_pk_max_f16
            }
        }
        #pragma unroll
        for (int mA = 0; mA < 2; mA++) {
            const int f = (mA * 4 + kb) * 64 + lane;
            half8v ah = *(const half8v*)&Wf[0][f * 8];
            half8v al = *(const half8v*)&Wf[1][f * 8];
            c2[mA] = __builtin_amdgcn_mfma_f32_32x32x16_f16(ah, zz.v, c2[mA], 0, 0, 0);
            c2[mA] = __builtin_amdgcn_mfma_f32_32x32x16_f16(al, zz.v, c2[mA], 0, 0, 0);
        }
    }

    // ---- refragment relu(c2) -> B3 f16 fragments (c2 dies here) ----
    half8v B3[4];
    #pragma unroll
    for (int kbp = 0; kbp < 4; kbp++) {
        const int mAs = kbp >> 1, kbl = kbp & 1;
        float fe[8];
        #pragma unroll
        for (int b = 0; b < 4; b++) {
            float u = fmaxf(c2[mAs][8 * kbl + b], 0.f);
            float v = fmaxf(c2[mAs][8 * kbl + 4 + b], 0.f);
            float su = __shfl_xor(u, 32, 64);
            float sv = __shfl_xor(v, 32, 64);
            fe[b]     = h ? sv : u;
            fe[4 + b] = h ? v : su;
        }
        half8v t8;
        #pragma unroll
        for (int q = 0; q < 8; q++) t8[q] = (_Float16)fe[q];   // v_cvt_f16_f32 pairs
        B3[kbp] = t8;
    }

    // ---- layer 3, bias init from LDS ----
    f32x16 c3[2];
    #pragma unroll
    for (int mA = 0; mA < 2; mA++)
        #pragma unroll
        for (int q = 0; q < 4; q++) {
            float4 b = *(const float4*)&mbS[1][mA * 32 + 4 * h + q * 8];
            c3[mA][q * 4 + 0] = b.x; c3[mA][q * 4 + 1] = b.y;
            c3[mA][q * 4 + 2] = b.z; c3[mA][q * 4 + 3] = b.w;
        }

    #pragma unroll
    for (int kbp = 0; kbp < 4; kbp++) {
        #pragma unroll
        for (int mA = 0; mA < 2; mA++) {
            const int f = (mA * 4 + kbp) * 64 + lane;
            half8v ah = *(const half8v*)&Wf[2][f * 8];
            half8v al = *(const half8v*)&Wf[3][f * 8];
            c3[mA] = __builtin_amdgcn_mfma_f32_32x32x16_f16(ah, B3[kbp], c3[mA], 0, 0, 0);
            c3[mA] = __builtin_amdgcn_mfma_f32_32x32x16_f16(al, B3[kbp], c3[mA], 0, 0, 0);
        }
    }

    float p = 0.f;
    #pragma unroll
    for (int mA = 0; mA < 2; mA++)
        #pragma unroll
        for (int q = 0; q < 4; q++) {
            float4 w4 = *(const float4*)&mbS[2][mA * 32 + 4 * h + q * 8];
            p = fmaf(fmaxf(c3[mA][q * 4 + 0], 0.f), w4.x, p);
            p = fmaf(fmaxf(c3[mA][q * 4 + 1], 0.f), w4.y, p);
            p = fmaf(fmaxf(c3[mA][q * 4 + 2], 0.f), w4.z, p);
            p = fmaf(fmaxf(c3[mA][q * 4 + 3], 0.f), w4.w, p);
        }
    p += __shfl_xor(p, 32, 64);
    int eA = e2[tbase + l31];
    if (lane < 32) out[eA] = p + mb4[0];
}

extern "C" void kernel_launch(void* const* d_in, const int* in_sizes, int n_in,
                              void* d_out, int out_size, void* d_ws, size_t ws_size,
                              hipStream_t stream) {
    const float* x   = (const float*)d_in[0];
    const int*   ei  = (const int*)d_in[1];
    const float* W1  = (const float*)d_in[2];
    const float* as1 = (const float*)d_in[3];
    const float* ad1 = (const float*)d_in[4];
    const float* b1  = (const float*)d_in[5];
    const float* W2  = (const float*)d_in[6];
    const float* as2 = (const float*)d_in[7];
    const float* ad2 = (const float*)d_in[8];
    const float* b2  = (const float*)d_in[9];
    const float* mW1 = (const float*)d_in[10];
    const float* mb1 = (const float*)d_in[11];
    const float* mW2 = (const float*)d_in[12];
    const float* mb2 = (const float*)d_in[13];
    const float* mW3 = (const float*)d_in[14];
    const float* mb3 = (const float*)d_in[15];
    const float* mW4 = (const float*)d_in[16];
    const float* mb4 = (const float*)d_in[17];
    float* out = (float*)d_out;
    const int* row = ei;             // src
    const int* col = ei + N_EDGES;   // dst

    char* w = (char*)d_ws;
    __half*   Uh    = (__half*)w;                     // 6.4 MB, k5b->k7g
    __half*   Vh    = (__half*)(w + 6400000);         // 6.4 MB, k5b->k7g
    float*    out2  = (float*)(w + 12800000);         // 12.8 MB, k5a->k5b
    __half*   h2h   = (__half*)(w + 25600000);        // 6.4 MB, k4n->k5a
    unsigned* ssd   = (unsigned*)(w + 32000000);      // 6.4 MB (CSR order, dst<<16|src)
    int*      eid   = (int*)(w + 38400000);           // 6.4 MB
    unsigned* s2sd  = (unsigned*)(w + 44800000);      // 6.4 MB (2D order)
    int*      eid2  = (int*)(w + 51200000);           // 6.4 MB
    int*      deg   = (int*)(w + 57600000);           // 0.2 MB
    int*      offp  = (int*)(w + 57800000);           // 0.2 MB + 4
    int*      cursor= (int*)(w + 58000064);           // 0.2 MB
    float*    al_s2 = (float*)(w + 58200064);
    float*    al_d2 = (float*)(w + 58400064);
    int*      bsum  = (int*)(w + 58600064);           // 4 KB (scan temps, reused)
    float*    qs    = (float*)(w + 58605056);
    float*    qd    = (float*)(w + 58605184);
    __half*   W2th  = (__half*)(w + 58605312);
    __half*   W2tl  = W2th + 4096;
    __half*   W3th  = W2th + 8192;
    __half*   W3tl  = W2th + 12288;                   // ends 58,638,080
    int*      cnt   = (int*)(w + 58638080);           // 7*NBLK*4 = 175 KB
    int*      basep = (int*)(w + 58813080);           // 175 KB
    int*      cnt1  = (int*)(w + 58988984 + 8);       // NB1*NBLK*4 = 800 KB
    int*      basep1= (int*)(w + 59789000);           // 800 KB
    int*      bsumA = (int*)(w + 60589000);           // 782*4
    // overlays:
    float*    accx  = (float*)(w + 12800000);         // 6.4 MB, k3n->k4n (inside out2)
    float*    denb  = (float*)(w + 19200000);         // 0.4 MB, k3n->k4n
    float*    al_s1 = (float*)(w + 19600000);         // 0.4 MB, k1n->k3n
    float*    al_d1 = (float*)(w + 20000000);         // 0.4 MB, k1n->k3n
    unsigned long long* tmp = (unsigned long long*)(w + 44800000);  // 12.8 MB, overlays s2sd+eid2 (dead until p_scatter)

    hipMemsetAsync(deg, 0, N_NODES * sizeof(int), stream);
    k_qprep<<<1, 64, 0, stream>>>(W1, as1, ad1, qs, qd);
    k_wprep<<<64, 64, 0, stream>>>(mW2, mW3, W2th, W2tl, W3th, W3tl);
    k1n<<<(N_NODES + 255) / 256, 256, 0, stream>>>(x, qs, qd, al_s1, al_d1);
    // histograms: global deg + per-block level-1 bucket counts
    s_hist1<<<NBLK, 256, 0, stream>>>(col, deg, cnt1);
    // CSR offsets
    k_scan1<<<(N_NODES + SCAN_B - 1) / SCAN_B, SCAN_B, 0, stream>>>(deg, offp, bsum);
    k_scan2<<<1, SCAN_B, 0, stream>>>(bsum, (N_NODES + SCAN_B - 1) / SCAN_B);
    k_scan3<<<(N_NODES + SCAN_B - 1) / SCAN_B, SCAN_B, 0, stream>>>(offp, bsum, cursor);
    // level-1 bucket bases: 3-level scan over cnt1[NB1][NBLK] (200000 entries)
    {
        int n1 = NB1 * NBLK;                          // 200000
        int nb1 = (n1 + SCAN_B - 1) / SCAN_B;         // 782
        int nb2 = (nb1 + SCAN_B - 1) / SCAN_B;        // 4
        g_scan1<<<nb1, SCAN_B, 0, stream>>>(cnt1, basep1, bsumA, n1);
        g_scan1<<<nb2, SCAN_B, 0, stream>>>(bsumA, bsumA, bsum, nb1);
        k_scan2<<<1, SCAN_B, 0, stream>>>(bsum, nb2);
        g_add<<<nb2, SCAN_B, 0, stream>>>(bsumA, bsum, nb1);
        g_add<<<nb1, SCAN_B, 0, stream>>>(basep1, bsumA, n1);
    }
    // hierarchical scatter: edges -> bucket-major tmp -> exact CSR slots
    s_scatter1<<<NBLK, 256, 0, stream>>>(row, col, basep1, tmp);
    s_scatter2<<<1024, 256, 0, stream>>>(tmp, cursor, ssd, eid);
    // 7-bucket src partition for k7g
    p_hist<<<NBLK, 256, 0, stream>>>(ssd, cnt);
    {
        int n = 7 * NBLK;                             // 43750
        int nbk = (n + SCAN_B - 1) / SCAN_B;          // 171
        g_scan1<<<nbk, SCAN_B, 0, stream>>>(cnt, basep, bsum, n);
        k_scan2<<<1, SCAN_B, 0, stream>>>(bsum, nbk);
        g_add<<<nbk, SCAN_B, 0, stream>>>(basep, bsum, n);
    }
    p_scatter<<<NBLK, 256, 0, stream>>>(ssd, eid, basep, s2sd, eid2);
    k3n<<<N_NODES / 8, 256, 0, stream>>>(x, al_s1, al_d1, offp, ssd, accx, denb);
    k4n<<<N_NODES / 4, 256, 0, stream>>>(accx, denb, W1, b1, W2, as2, ad2, h2h, al_s2, al_d2);
    k5a<<<N_NODES, 64, 0, stream>>>(h2h, al_s2, al_d2, b2, offp, ssd, out2);
    k5b<<<N_NODES / 4, 256, 0, stream>>>(out2, mW1, mb1, Uh, Vh);
    k7g<<<NBLK, 512, 0, stream>>>(s2sd, eid2, Uh, Vh,
                                  W2th, W2tl, W3th, W3tl,
                                  mb2, mb3, mW4, mb4, out);
}